// Round 6
// baseline (431.650 us; speedup 1.0000x reference)
//
#include <hip/hip_runtime.h>

// SAGAN self-attention, B=4, C=512, Cp=64, N=64*64=4096. fp32 in/out
// (runtime-detected). All GEMMs on bf16 MFMA 16x16x32.
// fxT/gxT stored transposed [n][c] (fxT pre-scaled by log2e); hx [c][n];
// opT [n][c] fp32 (atomic split-K). Softmax: l_i = sum_j exp2(s'_ij), no
// max-subtraction (|s| small). Attention passes are BARRIER-FREE: all MFMA
// operands loaded directly from global (contiguous-K rows), P transforms
// through per-wave-private LDS (in-wave DS ordering, no __syncthreads).

#define NB 4
#define CC 512
#define CP 64
#define NN 4096
#define ISPLIT 8
#define JSPLIT 8
#define LOG2E 1.4426950408889634f

typedef __attribute__((ext_vector_type(8))) short short8;
typedef __attribute__((ext_vector_type(4))) float floatx4;

__device__ __forceinline__ float bf2f_u(unsigned short h) {
    return __uint_as_float((unsigned)h << 16);
}
__device__ __forceinline__ float bf16lo(unsigned v) { return __uint_as_float(v << 16); }
__device__ __forceinline__ float bf16hi(unsigned v) { return __uint_as_float(v & 0xffff0000u); }
__device__ __forceinline__ unsigned short f2bf(float f) {
    unsigned u = __float_as_uint(f);
    u += 0x7fffu + ((u >> 16) & 1u);   // RNE
    return (unsigned short)(u >> 16);
}
__device__ __forceinline__ unsigned pack2bf(float a, float b) {
    return (unsigned)f2bf(a) | ((unsigned)f2bf(b) << 16);
}
__device__ __forceinline__ float ldS(const void* p, long i, int f32) {
    return f32 ? ((const float*)p)[i] : bf2f_u(((const unsigned short*)p)[i]);
}
__device__ __forceinline__ float2 ld2(const void* p, long i, int f32) {
    if (f32) return *reinterpret_cast<const float2*>((const float*)p + i);
    unsigned v = *reinterpret_cast<const unsigned*>((const unsigned short*)p + i);
    return make_float2(bf16lo(v), bf16hi(v));
}
__device__ __forceinline__ float4 ld4(const void* p, long i, int f32) {
    if (f32) return *reinterpret_cast<const float4*>((const float*)p + i);
    uint2 v = *reinterpret_cast<const uint2*>((const unsigned short*)p + i);
    return make_float4(bf16lo(v.x), bf16hi(v.x), bf16lo(v.y), bf16hi(v.y));
}
// 8 consecutive bf16 -> fragment (16B aligned)
__device__ __forceinline__ short8 fragbf(const unsigned short* p) {
    uint4 v = *reinterpret_cast<const uint4*>(p);
    return *reinterpret_cast<short8*>(&v);
}
// 8 consecutive fp32 (or bf16) -> bf16 fragment
__device__ __forceinline__ short8 frag8(const void* p, long i, int f32) {
    uint4 au;
    if (f32) {
        float4 v0 = *reinterpret_cast<const float4*>((const float*)p + i);
        float4 v1 = *reinterpret_cast<const float4*>((const float*)p + i + 4);
        au.x = pack2bf(v0.x, v0.y); au.y = pack2bf(v0.z, v0.w);
        au.z = pack2bf(v1.x, v1.y); au.w = pack2bf(v1.z, v1.w);
    } else {
        au = *reinterpret_cast<const uint4*>((const unsigned short*)p + i);
    }
    return *reinterpret_cast<short8*>(&au);
}

// ---------------------------------------------------------------------------
// dtype detector: 1 if fp32, 0 if bf16.
// ---------------------------------------------------------------------------
__global__ __launch_bounds__(256) void detect_kernel(
    const unsigned* __restrict__ x, int* __restrict__ flag)
{
    __shared__ int red[256];
    const int t = threadIdx.x;
    int bad = 0;
    for (int i = t; i < 4096; i += 256) {
        unsigned w = x[i];
        float f0 = __uint_as_float(w << 16);
        float f1 = __uint_as_float(w & 0xffff0000u);
        float a0 = fabsf(f0), a1 = fabsf(f1);
        if (!(a0 <= 1e3f) || (f0 != 0.f && a0 < 1e-20f)) bad++;
        if (!(a1 <= 1e3f) || (f1 != 0.f && a1 < 1e-20f)) bad++;
    }
    red[t] = bad;
    __syncthreads();
    for (int s = 128; s > 0; s >>= 1) { if (t < s) red[t] += red[t + s]; __syncthreads(); }
    if (t == 0) *flag = (red[0] > 64) ? 1 : 0;
}

// ---------------------------------------------------------------------------
// sigma: v = normalize(W^T u); sigma = u^T (W v); writes 1/sigma.
// ---------------------------------------------------------------------------
__global__ __launch_bounds__(512) void sigma_kernel(
    const void* __restrict__ Wf, const void* __restrict__ Wg,
    const void* __restrict__ Wh, const void* __restrict__ Wv,
    const void* __restrict__ uf, const void* __restrict__ ug,
    const void* __restrict__ uh, const void* __restrict__ uv,
    const int* __restrict__ dflag, float* __restrict__ sig)
{
    const int f32 = *dflag;
    const int w = blockIdx.x;
    const void* W;
    const void* u;
    int R, Cc, sh;
    if (w == 0)      { W = Wf; u = uf; R = 64;  Cc = 512; sh = 9; }
    else if (w == 1) { W = Wg; u = ug; R = 64;  Cc = 512; sh = 9; }
    else if (w == 2) { W = Wh; u = uh; R = 64;  Cc = 512; sh = 9; }
    else             { W = Wv; u = uv; R = 512; Cc = 64;  sh = 6; }

    __shared__ float us[512];
    __shared__ float vs[512];
    __shared__ float red[512];
    const int t = threadIdx.x;

    if (t < R) us[t] = ldS(u, t, f32);
    __syncthreads();

    if (t < Cc) {
        float a = 0.f;
        for (int i = 0; i < R; ++i) a += ldS(W, (long)(i << sh) + t, f32) * us[i];
        vs[t] = a;
    }
    __syncthreads();

    red[t] = (t < Cc) ? vs[t] * vs[t] : 0.f;
    __syncthreads();
    for (int s = 256; s > 0; s >>= 1) { if (t < s) red[t] += red[t + s]; __syncthreads(); }
    const float inv = 1.f / (sqrtf(red[0]) + 1e-12f);
    __syncthreads();
    if (t < Cc) vs[t] *= inv;
    __syncthreads();

    float a = 0.f;
    const int total = R * Cc;
    const int mask = Cc - 1;
    for (int idx = t; idx < total; idx += 512)
        a += us[idx >> sh] * ldS(W, idx, f32) * vs[idx & mask];
    red[t] = a;
    __syncthreads();
    for (int s = 256; s > 0; s >>= 1) { if (t < s) red[t] += red[t + s]; __syncthreads(); }
    if (t == 0) sig[w] = 1.f / red[0];
}

// ---------------------------------------------------------------------------
// proj (MFMA): out^T[n][c] = sum_k x^T[n][k] * (W/sigma)^T[k][c].
// fxT additionally scaled by log2e (softmax exp2 domain).
// ---------------------------------------------------------------------------
__global__ __launch_bounds__(256) void proj_kernel(
    const void* __restrict__ x,
    const void* __restrict__ Wf,
    const void* __restrict__ Wg,
    const void* __restrict__ Wh,
    const int* __restrict__ dflag,
    const float* __restrict__ sig,
    unsigned short* __restrict__ fxT, unsigned short* __restrict__ gxT,
    unsigned short* __restrict__ hx)
{
    const int f32 = *dflag;
    const int n0 = blockIdx.x * 64;
    const int b  = blockIdx.y;
    const int wi = blockIdx.z;
    const void* __restrict__ W = (wi == 0) ? Wf : ((wi == 1) ? Wg : Wh);
    const float scale = sig[wi] * ((wi == 0) ? LOG2E : 1.f);

    __shared__ unsigned short Wl[64][72];

    const int t = threadIdx.x;
    const int wv = t >> 6, l = t & 63, l15 = l & 15, quad = l >> 4;
    const int n = n0 + 16 * wv + l15;

    floatx4 acc[4];
    #pragma unroll
    for (int ct = 0; ct < 4; ++ct) acc[ct] = (floatx4){0.f, 0.f, 0.f, 0.f};

    for (int kc = 0; kc < CC; kc += 64) {
        #pragma unroll
        for (int idx = t; idx < 2048; idx += 256) {
            int c  = idx >> 5;
            int kk = (idx & 31) * 2;
            float2 v = ld2(W, (long)c * CC + kc + kk, f32);
            *reinterpret_cast<unsigned*>(&Wl[c][kk]) = pack2bf(v.x * scale, v.y * scale);
        }
        __syncthreads();

        #pragma unroll
        for (int ks = 0; ks < 2; ++ks) {
            const int kbase = kc + ks * 32 + quad * 8;
            float xv[8];
            #pragma unroll
            for (int j = 0; j < 8; ++j)
                xv[j] = ldS(x, ((long)b * CC + kbase + j) * NN + n, f32);
            uint4 au;
            au.x = pack2bf(xv[0], xv[1]); au.y = pack2bf(xv[2], xv[3]);
            au.z = pack2bf(xv[4], xv[5]); au.w = pack2bf(xv[6], xv[7]);
            short8 a = *reinterpret_cast<short8*>(&au);
            #pragma unroll
            for (int ct = 0; ct < 4; ++ct) {
                short8 bfr = *reinterpret_cast<const short8*>(
                    &Wl[ct * 16 + l15][ks * 32 + quad * 8]);
                acc[ct] = __builtin_amdgcn_mfma_f32_16x16x32_bf16(a, bfr, acc[ct], 0, 0, 0);
            }
        }
        __syncthreads();
    }

    if (wi < 2) {
        unsigned short* __restrict__ dstT = (wi == 0) ? fxT : gxT;
        #pragma unroll
        for (int ct = 0; ct < 4; ++ct)
            #pragma unroll
            for (int r = 0; r < 4; ++r)
                dstT[((size_t)b * NN + n0 + 16 * wv + quad * 4 + r) * 64 + ct * 16 + l15] =
                    f2bf(acc[ct][r]);
    } else {
        #pragma unroll
        for (int ct = 0; ct < 4; ++ct) {
            uint2 o;
            o.x = pack2bf(acc[ct][0], acc[ct][1]);
            o.y = pack2bf(acc[ct][2], acc[ct][3]);
            *reinterpret_cast<uint2*>(
                &hx[((size_t)b * CP + ct * 16 + l15) * NN + n0 + 16 * wv + quad * 4]) = o;
        }
    }
}

// ---------------------------------------------------------------------------
// rowstats (MFMA, barrier-free, no LDS): rl[b,i] += sum_j exp2(s'_ij).
// Wave owns 32 i (frags resident in regs); gx frags streamed from global.
// grid (NN/128, JSPLIT, NB).
// ---------------------------------------------------------------------------
__global__ __launch_bounds__(256) void rowstats_kernel(
    const unsigned short* __restrict__ fxT, const unsigned short* __restrict__ gxT,
    float* __restrict__ rl)
{
    const int iblk  = blockIdx.x * 128;
    const int jbase = blockIdx.y * (NN / JSPLIT);
    const int b     = blockIdx.z;
    const int t = threadIdx.x;
    const int w = t >> 6, l = t & 63, l15 = l & 15, quad = l >> 4;
    const int iown = iblk + w * 32;

    short8 a[2][2];
    #pragma unroll
    for (int isub = 0; isub < 2; ++isub)
        #pragma unroll
        for (int kh = 0; kh < 2; ++kh)
            a[isub][kh] = fragbf(fxT +
                ((size_t)b * NN + iown + isub * 16 + l15) * 64 + kh * 32 + quad * 8);

    float suml[2][4];
    #pragma unroll
    for (int isub = 0; isub < 2; ++isub)
        #pragma unroll
        for (int r = 0; r < 4; ++r) suml[isub][r] = 0.f;

    for (int jt = 0; jt < NN / JSPLIT; jt += 64) {
        #pragma unroll
        for (int jsub = 0; jsub < 4; ++jsub) {
            const unsigned short* gp =
                gxT + ((size_t)b * NN + jbase + jt + jsub * 16 + l15) * 64 + quad * 8;
            short8 g0 = fragbf(gp);
            short8 g1 = fragbf(gp + 32);
            #pragma unroll
            for (int isub = 0; isub < 2; ++isub) {
                floatx4 s = {0.f, 0.f, 0.f, 0.f};
                s = __builtin_amdgcn_mfma_f32_16x16x32_bf16(a[isub][0], g0, s, 0, 0, 0);
                s = __builtin_amdgcn_mfma_f32_16x16x32_bf16(a[isub][1], g1, s, 0, 0, 0);
                #pragma unroll
                for (int r = 0; r < 4; ++r) suml[isub][r] += exp2f(s[r]);
            }
        }
    }

    #pragma unroll
    for (int isub = 0; isub < 2; ++isub)
        #pragma unroll
        for (int r = 0; r < 4; ++r) {
            float v = suml[isub][r];
            v += __shfl_xor(v, 1);
            v += __shfl_xor(v, 2);
            v += __shfl_xor(v, 4);
            v += __shfl_xor(v, 8);
            if (l15 == 0)
                atomicAdd(&rl[(size_t)b * NN + iown + isub * 16 + quad * 4 + r], v);
        }
}

// ---------------------------------------------------------------------------
// pv (MFMA, barrier-free K-loop): opT[b,j,c] += sum_i hx[c,i]*exp2(s')/l_i.
// Wave owns 32 j (gx frags resident). fx/hx frags direct from global.
// P transform through per-wave-private LDS (no cross-wave sharing).
// grid (NN/128, ISPLIT, NB).
// ---------------------------------------------------------------------------
__global__ __launch_bounds__(256) void pv_kernel(
    const unsigned short* __restrict__ fxT, const unsigned short* __restrict__ gxT,
    const unsigned short* __restrict__ hx, const float* __restrict__ rl,
    float* __restrict__ opT)
{
    const int j0    = blockIdx.x * 128;
    const int ibase = blockIdx.y * (NN / ISPLIT);
    const int b     = blockIdx.z;
    const int t = threadIdx.x;
    const int w = t >> 6, l = t & 63, l15 = l & 15, quad = l >> 4;
    const int jw = j0 + w * 32;

    __shared__ float rli[NN / ISPLIT];                    // 2 KB
    __shared__ __align__(16) unsigned short plT[4][32][72]; // 18.4 KB, per-wave

    for (int idx = t; idx < NN / ISPLIT; idx += 256)
        rli[idx] = 1.f / rl[(size_t)b * NN + ibase + idx];
    __syncthreads();   // the only block-wide barrier

    short8 g[2][2];
    #pragma unroll
    for (int jt = 0; jt < 2; ++jt)
        #pragma unroll
        for (int kh = 0; kh < 2; ++kh)
            g[jt][kh] = fragbf(gxT +
                ((size_t)b * NN + jw + jt * 16 + l15) * 64 + kh * 32 + quad * 8);

    floatx4 oacc[4][2];
    #pragma unroll
    for (int cs = 0; cs < 4; ++cs)
        #pragma unroll
        for (int jt = 0; jt < 2; ++jt) oacc[cs][jt] = (floatx4){0.f, 0.f, 0.f, 0.f};

    for (int it = 0; it < NN / ISPLIT; it += 64) {
        const int i0 = ibase + it;
        short8 a[4][2], h[4][2];
        #pragma unroll
        for (int isub = 0; isub < 4; ++isub)
            #pragma unroll
            for (int kh = 0; kh < 2; ++kh)
                a[isub][kh] = fragbf(fxT +
                    ((size_t)b * NN + i0 + isub * 16 + l15) * 64 + kh * 32 + quad * 8);
        #pragma unroll
        for (int cs = 0; cs < 4; ++cs)
            #pragma unroll
            for (int kh = 0; kh < 2; ++kh)
                h[cs][kh] = fragbf(hx +
                    ((size_t)b * CP + cs * 16 + l15) * NN + i0 + kh * 32 + quad * 8);

        // S tiles -> p -> per-wave plT[j][i]
        #pragma unroll
        for (int isub = 0; isub < 4; ++isub)
            #pragma unroll
            for (int jt = 0; jt < 2; ++jt) {
                floatx4 s = {0.f, 0.f, 0.f, 0.f};
                s = __builtin_amdgcn_mfma_f32_16x16x32_bf16(a[isub][0], g[jt][0], s, 0, 0, 0);
                s = __builtin_amdgcn_mfma_f32_16x16x32_bf16(a[isub][1], g[jt][1], s, 0, 0, 0);
                const int il = it + isub * 16 + quad * 4;
                float p0 = exp2f(s[0]) * rli[il + 0];
                float p1 = exp2f(s[1]) * rli[il + 1];
                float p2 = exp2f(s[2]) * rli[il + 2];
                float p3 = exp2f(s[3]) * rli[il + 3];
                uint2 o;
                o.x = pack2bf(p0, p1);
                o.y = pack2bf(p2, p3);
                *reinterpret_cast<uint2*>(&plT[w][jt * 16 + l15][isub * 16 + quad * 4]) = o;
            }

        // PV: oacc[c,j] += h[c,i] * p[i,j]   (reads own wave's plT)
        #pragma unroll
        for (int jt = 0; jt < 2; ++jt) {
            short8 p0f = *reinterpret_cast<const short8*>(&plT[w][jt * 16 + l15][quad * 8]);
            short8 p1f = *reinterpret_cast<const short8*>(&plT[w][jt * 16 + l15][32 + quad * 8]);
            #pragma unroll
            for (int cs = 0; cs < 4; ++cs) {
                oacc[cs][jt] = __builtin_amdgcn_mfma_f32_16x16x32_bf16(h[cs][0], p0f, oacc[cs][jt], 0, 0, 0);
                oacc[cs][jt] = __builtin_amdgcn_mfma_f32_16x16x32_bf16(h[cs][1], p1f, oacc[cs][jt], 0, 0, 0);
            }
        }
    }

    #pragma unroll
    for (int cs = 0; cs < 4; ++cs)
        #pragma unroll
        for (int jt = 0; jt < 2; ++jt)
            #pragma unroll
            for (int r = 0; r < 4; ++r)
                atomicAdd(&opT[((size_t)b * NN + jw + jt * 16 + l15) * CP + cs * 16 + quad * 4 + r],
                          oacc[cs][jt][r]);
}

// ---------------------------------------------------------------------------
// outproj (MFMA): y^T[n][co] = scale * sum_cp opT[n][cp] Wv^T[cp][co] + x.
// ---------------------------------------------------------------------------
__global__ __launch_bounds__(256) void outproj_kernel(
    const void* __restrict__ x,
    const void* __restrict__ Wv,
    const void* __restrict__ gamma,
    const int* __restrict__ dflag,
    const float* __restrict__ sig,
    const float* __restrict__ opT,
    void* __restrict__ y)
{
    const int f32 = *dflag;
    const int n0     = blockIdx.x * 64;
    const int cobase = blockIdx.y * 128;
    const int b      = blockIdx.z;
    const int t = threadIdx.x;
    const int wv = t >> 6, l = t & 63, l15 = l & 15, quad = l >> 4;
    const float scale = ldS(gamma, 0, f32) * sig[3];

    floatx4 acc[4][2];
    #pragma unroll
    for (int ns = 0; ns < 4; ++ns)
        #pragma unroll
        for (int ct = 0; ct < 2; ++ct) acc[ns][ct] = (floatx4){0.f, 0.f, 0.f, 0.f};

    #pragma unroll
    for (int ks = 0; ks < 2; ++ks) {
        const int kb = ks * 32 + quad * 8;
        short8 a[4];
        #pragma unroll
        for (int ns = 0; ns < 4; ++ns)
            a[ns] = frag8(opT, ((long)b * NN + n0 + 16 * ns + l15) * CP + kb, 1);
        #pragma unroll
        for (int ct = 0; ct < 2; ++ct) {
            const int co = cobase + 32 * wv + 16 * ct + l15;
            short8 bfr = frag8(Wv, (long)co * CP + kb, f32);
            #pragma unroll
            for (int ns = 0; ns < 4; ++ns)
                acc[ns][ct] = __builtin_amdgcn_mfma_f32_16x16x32_bf16(a[ns], bfr, acc[ns][ct], 0, 0, 0);
        }
    }

    #pragma unroll
    for (int ns = 0; ns < 4; ++ns)
        #pragma unroll
        for (int ct = 0; ct < 2; ++ct) {
            const int co = cobase + 32 * wv + 16 * ct + l15;
            const long base = ((long)b * CC + co) * NN + n0 + 16 * ns + quad * 4;
            float4 xv = ld4(x, base, f32);
            float o0 = fmaf(scale, acc[ns][ct][0], xv.x);
            float o1 = fmaf(scale, acc[ns][ct][1], xv.y);
            float o2 = fmaf(scale, acc[ns][ct][2], xv.z);
            float o3 = fmaf(scale, acc[ns][ct][3], xv.w);
            if (f32) {
                *reinterpret_cast<float4*>((float*)y + base) = make_float4(o0, o1, o2, o3);
            } else {
                uint2 o;
                o.x = pack2bf(o0, o1);
                o.y = pack2bf(o2, o3);
                *reinterpret_cast<uint2*>((unsigned short*)y + base) = o;
            }
        }
}

// ---------------------------------------------------------------------------
extern "C" void kernel_launch(void* const* d_in, const int* in_sizes, int n_in,
                              void* d_out, int out_size, void* d_ws, size_t ws_size,
                              hipStream_t stream)
{
    const void* x  = d_in[0];
    const void* Wf = d_in[1];
    const void* Wg = d_in[2];
    const void* Wh = d_in[3];
    const void* Wv = d_in[4];
    const void* uf = d_in[5];
    const void* ug = d_in[6];
    const void* uh = d_in[7];
    const void* uv = d_in[8];
    const void* gm = d_in[9];

    // ws: dfl | sig | rl (64KB) | opT (4MB fp32) | fxT | gxT | hx (2MB bf16 each)
    char* base = (char*)d_ws;
    int*   dfl = (int*)(base);
    float* sig = (float*)(base + 512);
    float* rl  = (float*)(base + 1024);
    float* opT = (float*)(base + 1024 + 65536);
    unsigned short* fxT = (unsigned short*)(base + 1024 + 65536 + 4194304);
    unsigned short* gxT = fxT + (size_t)NB * CP * NN;
    unsigned short* hx  = gxT + (size_t)NB * CP * NN;

    hipMemsetAsync(rl, 0, 65536 + 4194304, stream);

    hipLaunchKernelGGL(detect_kernel, dim3(1), dim3(256), 0, stream,
                       (const unsigned*)x, dfl);
    hipLaunchKernelGGL(sigma_kernel, dim3(4), dim3(512), 0, stream,
                       Wf, Wg, Wh, Wv, uf, ug, uh, uv, dfl, sig);
    hipLaunchKernelGGL(proj_kernel, dim3(NN / 64, NB, 3), dim3(256), 0, stream,
                       x, Wf, Wg, Wh, dfl, sig, fxT, gxT, hx);
    hipLaunchKernelGGL(rowstats_kernel, dim3(NN / 128, JSPLIT, NB), dim3(256), 0, stream,
                       fxT, gxT, rl);
    hipLaunchKernelGGL(pv_kernel, dim3(NN / 128, ISPLIT, NB), dim3(256), 0, stream,
                       fxT, gxT, hx, rl, opT);
    hipLaunchKernelGGL(outproj_kernel, dim3(NN / 64, CC / 128, NB), dim3(256), 0, stream,
                       x, Wv, gm, dfl, sig, opT, d_out);
}

// Round 7
// 415.495 us; speedup vs baseline: 1.0389x; 1.0389x over previous
//
#include <hip/hip_runtime.h>

// SAGAN self-attention, B=4, C=512, Cp=64, N=64*64=4096. fp32 in/out
// (runtime-detected). All GEMMs on bf16 MFMA 16x16x32.
// fxT/gxT transposed [n][c] (fxT pre-scaled by log2e); hx [c][n];
// opT [n][c] fp32 (atomic split-K). Softmax: l_i = sum_j exp2(s'),
// no max-subtraction (|s'| < ~2). Attention kernels: shared operands
// (fx/hx or gx tiles) staged in LDS (x4 wave reuse), next tile prefetched
// into registers during compute; P transform via per-wave-private LDS
// (in-wave DS ordering, no barrier). 2 barriers per K-iter.

#define NB 4
#define CC 512
#define CP 64
#define NN 4096
#define ISPLIT 8
#define JSPLIT 8
#define LOG2E 1.4426950408889634f

typedef __attribute__((ext_vector_type(8))) short short8;
typedef __attribute__((ext_vector_type(4))) float floatx4;

__device__ __forceinline__ float bf2f_u(unsigned short h) {
    return __uint_as_float((unsigned)h << 16);
}
__device__ __forceinline__ float bf16lo(unsigned v) { return __uint_as_float(v << 16); }
__device__ __forceinline__ float bf16hi(unsigned v) { return __uint_as_float(v & 0xffff0000u); }
__device__ __forceinline__ unsigned short f2bf(float f) {
    unsigned u = __float_as_uint(f);
    u += 0x7fffu + ((u >> 16) & 1u);   // RNE
    return (unsigned short)(u >> 16);
}
__device__ __forceinline__ unsigned pack2bf(float a, float b) {
    return (unsigned)f2bf(a) | ((unsigned)f2bf(b) << 16);
}
__device__ __forceinline__ float ldS(const void* p, long i, int f32) {
    return f32 ? ((const float*)p)[i] : bf2f_u(((const unsigned short*)p)[i]);
}
__device__ __forceinline__ float2 ld2(const void* p, long i, int f32) {
    if (f32) return *reinterpret_cast<const float2*>((const float*)p + i);
    unsigned v = *reinterpret_cast<const unsigned*>((const unsigned short*)p + i);
    return make_float2(bf16lo(v), bf16hi(v));
}
__device__ __forceinline__ float4 ld4(const void* p, long i, int f32) {
    if (f32) return *reinterpret_cast<const float4*>((const float*)p + i);
    uint2 v = *reinterpret_cast<const uint2*>((const unsigned short*)p + i);
    return make_float4(bf16lo(v.x), bf16hi(v.x), bf16lo(v.y), bf16hi(v.y));
}
__device__ __forceinline__ short8 fragbf(const unsigned short* p) {
    uint4 v = *reinterpret_cast<const uint4*>(p);
    return *reinterpret_cast<short8*>(&v);
}
__device__ __forceinline__ short8 frag8(const void* p, long i, int f32) {
    uint4 au;
    if (f32) {
        float4 v0 = *reinterpret_cast<const float4*>((const float*)p + i);
        float4 v1 = *reinterpret_cast<const float4*>((const float*)p + i + 4);
        au.x = pack2bf(v0.x, v0.y); au.y = pack2bf(v0.z, v0.w);
        au.z = pack2bf(v1.x, v1.y); au.w = pack2bf(v1.z, v1.w);
    } else {
        au = *reinterpret_cast<const uint4*>((const unsigned short*)p + i);
    }
    return *reinterpret_cast<short8*>(&au);
}

// ---------------------------------------------------------------------------
// dtype detector: 1 if fp32, 0 if bf16.
// ---------------------------------------------------------------------------
__global__ __launch_bounds__(256) void detect_kernel(
    const unsigned* __restrict__ x, int* __restrict__ flag)
{
    __shared__ int red[256];
    const int t = threadIdx.x;
    int bad = 0;
    for (int i = t; i < 4096; i += 256) {
        unsigned w = x[i];
        float f0 = __uint_as_float(w << 16);
        float f1 = __uint_as_float(w & 0xffff0000u);
        float a0 = fabsf(f0), a1 = fabsf(f1);
        if (!(a0 <= 1e3f) || (f0 != 0.f && a0 < 1e-20f)) bad++;
        if (!(a1 <= 1e3f) || (f1 != 0.f && a1 < 1e-20f)) bad++;
    }
    red[t] = bad;
    __syncthreads();
    for (int s = 128; s > 0; s >>= 1) { if (t < s) red[t] += red[t + s]; __syncthreads(); }
    if (t == 0) *flag = (red[0] > 64) ? 1 : 0;
}

// ---------------------------------------------------------------------------
// sigma: v = normalize(W^T u); sigma = u^T (W v); writes 1/sigma.
// ---------------------------------------------------------------------------
__global__ __launch_bounds__(512) void sigma_kernel(
    const void* __restrict__ Wf, const void* __restrict__ Wg,
    const void* __restrict__ Wh, const void* __restrict__ Wv,
    const void* __restrict__ uf, const void* __restrict__ ug,
    const void* __restrict__ uh, const void* __restrict__ uv,
    const int* __restrict__ dflag, float* __restrict__ sig)
{
    const int f32 = *dflag;
    const int w = blockIdx.x;
    const void* W;
    const void* u;
    int R, Cc, sh;
    if (w == 0)      { W = Wf; u = uf; R = 64;  Cc = 512; sh = 9; }
    else if (w == 1) { W = Wg; u = ug; R = 64;  Cc = 512; sh = 9; }
    else if (w == 2) { W = Wh; u = uh; R = 64;  Cc = 512; sh = 9; }
    else             { W = Wv; u = uv; R = 512; Cc = 64;  sh = 6; }

    __shared__ float us[512];
    __shared__ float vs[512];
    __shared__ float red[512];
    const int t = threadIdx.x;

    if (t < R) us[t] = ldS(u, t, f32);
    __syncthreads();

    if (t < Cc) {
        float a = 0.f;
        for (int i = 0; i < R; ++i) a += ldS(W, (long)(i << sh) + t, f32) * us[i];
        vs[t] = a;
    }
    __syncthreads();

    red[t] = (t < Cc) ? vs[t] * vs[t] : 0.f;
    __syncthreads();
    for (int s = 256; s > 0; s >>= 1) { if (t < s) red[t] += red[t + s]; __syncthreads(); }
    const float inv = 1.f / (sqrtf(red[0]) + 1e-12f);
    __syncthreads();
    if (t < Cc) vs[t] *= inv;
    __syncthreads();

    float a = 0.f;
    const int total = R * Cc;
    const int mask = Cc - 1;
    for (int idx = t; idx < total; idx += 512)
        a += us[idx >> sh] * ldS(W, idx, f32) * vs[idx & mask];
    red[t] = a;
    __syncthreads();
    for (int s = 256; s > 0; s >>= 1) { if (t < s) red[t] += red[t + s]; __syncthreads(); }
    if (t == 0) sig[w] = 1.f / red[0];
}

// ---------------------------------------------------------------------------
// proj (MFMA): out^T[n][c] = sum_k x^T[n][k] * (W/sigma)^T[k][c].
// fxT additionally scaled by log2e (softmax exp2 domain).
// ---------------------------------------------------------------------------
__global__ __launch_bounds__(256) void proj_kernel(
    const void* __restrict__ x,
    const void* __restrict__ Wf,
    const void* __restrict__ Wg,
    const void* __restrict__ Wh,
    const int* __restrict__ dflag,
    const float* __restrict__ sig,
    unsigned short* __restrict__ fxT, unsigned short* __restrict__ gxT,
    unsigned short* __restrict__ hx)
{
    const int f32 = *dflag;
    const int n0 = blockIdx.x * 64;
    const int b  = blockIdx.y;
    const int wi = blockIdx.z;
    const void* __restrict__ W = (wi == 0) ? Wf : ((wi == 1) ? Wg : Wh);
    const float scale = sig[wi] * ((wi == 0) ? LOG2E : 1.f);

    __shared__ unsigned short Wl[64][72];

    const int t = threadIdx.x;
    const int wv = t >> 6, l = t & 63, l15 = l & 15, quad = l >> 4;
    const int n = n0 + 16 * wv + l15;

    floatx4 acc[4];
    #pragma unroll
    for (int ct = 0; ct < 4; ++ct) acc[ct] = (floatx4){0.f, 0.f, 0.f, 0.f};

    for (int kc = 0; kc < CC; kc += 64) {
        #pragma unroll
        for (int idx = t; idx < 2048; idx += 256) {
            int c  = idx >> 5;
            int kk = (idx & 31) * 2;
            float2 v = ld2(W, (long)c * CC + kc + kk, f32);
            *reinterpret_cast<unsigned*>(&Wl[c][kk]) = pack2bf(v.x * scale, v.y * scale);
        }
        __syncthreads();

        #pragma unroll
        for (int ks = 0; ks < 2; ++ks) {
            const int kbase = kc + ks * 32 + quad * 8;
            float xv[8];
            #pragma unroll
            for (int j = 0; j < 8; ++j)
                xv[j] = ldS(x, ((long)b * CC + kbase + j) * NN + n, f32);
            uint4 au;
            au.x = pack2bf(xv[0], xv[1]); au.y = pack2bf(xv[2], xv[3]);
            au.z = pack2bf(xv[4], xv[5]); au.w = pack2bf(xv[6], xv[7]);
            short8 a = *reinterpret_cast<short8*>(&au);
            #pragma unroll
            for (int ct = 0; ct < 4; ++ct) {
                short8 bfr = *reinterpret_cast<const short8*>(
                    &Wl[ct * 16 + l15][ks * 32 + quad * 8]);
                acc[ct] = __builtin_amdgcn_mfma_f32_16x16x32_bf16(a, bfr, acc[ct], 0, 0, 0);
            }
        }
        __syncthreads();
    }

    if (wi < 2) {
        unsigned short* __restrict__ dstT = (wi == 0) ? fxT : gxT;
        #pragma unroll
        for (int ct = 0; ct < 4; ++ct)
            #pragma unroll
            for (int r = 0; r < 4; ++r)
                dstT[((size_t)b * NN + n0 + 16 * wv + quad * 4 + r) * 64 + ct * 16 + l15] =
                    f2bf(acc[ct][r]);
    } else {
        #pragma unroll
        for (int ct = 0; ct < 4; ++ct) {
            uint2 o;
            o.x = pack2bf(acc[ct][0], acc[ct][1]);
            o.y = pack2bf(acc[ct][2], acc[ct][3]);
            *reinterpret_cast<uint2*>(
                &hx[((size_t)b * CP + ct * 16 + l15) * NN + n0 + 16 * wv + quad * 4]) = o;
        }
    }
}

// ---------------------------------------------------------------------------
// rowstats (MFMA): rl[b,i] += sum_j exp2(s'_ij) over this block's j-range.
// Block = 128 i (wave owns 32 i, fx frags reg-resident). gx tile (64 j)
// LDS-staged, reg-prefetch double-buffered. grid (NN/128, JSPLIT, NB).
// ---------------------------------------------------------------------------
__global__ __launch_bounds__(256) void rowstats_kernel(
    const unsigned short* __restrict__ fxT, const unsigned short* __restrict__ gxT,
    float* __restrict__ rl)
{
    const int iblk  = blockIdx.x * 128;
    const int jbase = blockIdx.y * (NN / JSPLIT);
    const int b     = blockIdx.z;
    const int t = threadIdx.x;
    const int w = t >> 6, l = t & 63, l15 = l & 15, quad = l >> 4;
    const int iown = iblk + w * 32;

    __shared__ __align__(16) unsigned short gxs[64][72];

    // wave-resident fx fragments (32 i)
    short8 a[2][2];
    #pragma unroll
    for (int isub = 0; isub < 2; ++isub)
        #pragma unroll
        for (int kh = 0; kh < 2; ++kh)
            a[isub][kh] = fragbf(fxT +
                ((size_t)b * NN + iown + isub * 16 + l15) * 64 + kh * 32 + quad * 8);

    // prefetch first gx tile
    uint4 pf[2];
    #pragma unroll
    for (int k = 0; k < 2; ++k) {
        int idx = t + k * 256;
        pf[k] = *reinterpret_cast<const uint4*>(
            gxT + ((size_t)b * NN + jbase + (idx >> 3)) * 64 + (idx & 7) * 8);
    }

    float suml[2][4];
    #pragma unroll
    for (int isub = 0; isub < 2; ++isub)
        #pragma unroll
        for (int r = 0; r < 4; ++r) suml[isub][r] = 0.f;

    const int NJ = NN / JSPLIT;
    for (int jt = 0; jt < NJ; jt += 64) {
        #pragma unroll
        for (int k = 0; k < 2; ++k) {
            int idx = t + k * 256;
            *reinterpret_cast<uint4*>(&gxs[idx >> 3][(idx & 7) * 8]) = pf[k];
        }
        __syncthreads();
        if (jt + 64 < NJ) {
            #pragma unroll
            for (int k = 0; k < 2; ++k) {
                int idx = t + k * 256;
                pf[k] = *reinterpret_cast<const uint4*>(
                    gxT + ((size_t)b * NN + jbase + jt + 64 + (idx >> 3)) * 64 + (idx & 7) * 8);
            }
        }
        #pragma unroll
        for (int jsub = 0; jsub < 4; ++jsub) {
            short8 g0 = *reinterpret_cast<const short8*>(&gxs[jsub * 16 + l15][quad * 8]);
            short8 g1 = *reinterpret_cast<const short8*>(&gxs[jsub * 16 + l15][32 + quad * 8]);
            #pragma unroll
            for (int isub = 0; isub < 2; ++isub) {
                floatx4 s = {0.f, 0.f, 0.f, 0.f};
                s = __builtin_amdgcn_mfma_f32_16x16x32_bf16(a[isub][0], g0, s, 0, 0, 0);
                s = __builtin_amdgcn_mfma_f32_16x16x32_bf16(a[isub][1], g1, s, 0, 0, 0);
                #pragma unroll
                for (int r = 0; r < 4; ++r) suml[isub][r] += exp2f(s[r]);
            }
        }
        __syncthreads();
    }

    #pragma unroll
    for (int isub = 0; isub < 2; ++isub)
        #pragma unroll
        for (int r = 0; r < 4; ++r) {
            float v = suml[isub][r];
            v += __shfl_xor(v, 1);
            v += __shfl_xor(v, 2);
            v += __shfl_xor(v, 4);
            v += __shfl_xor(v, 8);
            if (l15 == 0)
                atomicAdd(&rl[(size_t)b * NN + iown + isub * 16 + quad * 4 + r], v);
        }
}

// ---------------------------------------------------------------------------
// pv (MFMA): opT[b,j,c] += sum_i hx[c,i]*exp2(s')/l_i over this i-range.
// Block = 128 j (wave owns 32 j, gx frags reg-resident). fx+hx tiles (64 i)
// LDS-staged shared by 4 waves, reg-prefetch double-buffered. P via
// per-wave-private LDS. grid (NN/128, ISPLIT, NB). 2 barriers/iter.
// ---------------------------------------------------------------------------
__global__ __launch_bounds__(256) void pv_kernel(
    const unsigned short* __restrict__ fxT, const unsigned short* __restrict__ gxT,
    const unsigned short* __restrict__ hx, const float* __restrict__ rl,
    float* __restrict__ opT)
{
    const int j0    = blockIdx.x * 128;
    const int ibase = blockIdx.y * (NN / ISPLIT);
    const int b     = blockIdx.z;
    const int t = threadIdx.x;
    const int w = t >> 6, l = t & 63, l15 = l & 15, quad = l >> 4;
    const int jw = j0 + w * 32;

    __shared__ __align__(16) unsigned short fxs[64][72];     // [i][c]
    __shared__ __align__(16) unsigned short hxs[64][72];     // [c][i]
    __shared__ __align__(16) unsigned short plT[4][32][72];  // per-wave [j][i]
    __shared__ float rli[NN / ISPLIT];                        // 2 KB

    for (int idx = t; idx < NN / ISPLIT; idx += 256)
        rli[idx] = 1.f / rl[(size_t)b * NN + ibase + idx];

    // wave-resident gx fragments (32 j)
    short8 g[2][2];
    #pragma unroll
    for (int jt = 0; jt < 2; ++jt)
        #pragma unroll
        for (int kh = 0; kh < 2; ++kh)
            g[jt][kh] = fragbf(gxT +
                ((size_t)b * NN + jw + jt * 16 + l15) * 64 + kh * 32 + quad * 8);

    // prefetch first fx/hx tile into registers
    uint4 pf_f[2], pf_h[2];
    #pragma unroll
    for (int k = 0; k < 2; ++k) {
        int idx = t + k * 256;
        pf_f[k] = *reinterpret_cast<const uint4*>(
            fxT + ((size_t)b * NN + ibase + (idx >> 3)) * 64 + (idx & 7) * 8);
        pf_h[k] = *reinterpret_cast<const uint4*>(
            hx + ((size_t)b * CP + (idx >> 3)) * NN + ibase + (idx & 7) * 8);
    }

    floatx4 oacc[4][2];
    #pragma unroll
    for (int cs = 0; cs < 4; ++cs)
        #pragma unroll
        for (int jt = 0; jt < 2; ++jt) oacc[cs][jt] = (floatx4){0.f, 0.f, 0.f, 0.f};

    const int NI = NN / ISPLIT;
    for (int it = 0; it < NI; it += 64) {
        // commit prefetched tile to LDS
        #pragma unroll
        for (int k = 0; k < 2; ++k) {
            int idx = t + k * 256;
            *reinterpret_cast<uint4*>(&fxs[idx >> 3][(idx & 7) * 8]) = pf_f[k];
            *reinterpret_cast<uint4*>(&hxs[idx >> 3][(idx & 7) * 8]) = pf_h[k];
        }
        __syncthreads();   // tile (and first-iter rli) visible

        // prefetch next tile (overlaps with compute below)
        if (it + 64 < NI) {
            const int i1 = ibase + it + 64;
            #pragma unroll
            for (int k = 0; k < 2; ++k) {
                int idx = t + k * 256;
                pf_f[k] = *reinterpret_cast<const uint4*>(
                    fxT + ((size_t)b * NN + i1 + (idx >> 3)) * 64 + (idx & 7) * 8);
                pf_h[k] = *reinterpret_cast<const uint4*>(
                    hx + ((size_t)b * CP + (idx >> 3)) * NN + i1 + (idx & 7) * 8);
            }
        }

        float4 rv[4];
        #pragma unroll
        for (int isub = 0; isub < 4; ++isub)
            rv[isub] = *reinterpret_cast<const float4*>(&rli[it + isub * 16 + quad * 4]);

        short8 a[4][2], hh[4][2];
        #pragma unroll
        for (int isub = 0; isub < 4; ++isub)
            #pragma unroll
            for (int kh = 0; kh < 2; ++kh)
                a[isub][kh] = *reinterpret_cast<const short8*>(
                    &fxs[isub * 16 + l15][kh * 32 + quad * 8]);
        #pragma unroll
        for (int cs = 0; cs < 4; ++cs)
            #pragma unroll
            for (int kh = 0; kh < 2; ++kh)
                hh[cs][kh] = *reinterpret_cast<const short8*>(
                    &hxs[cs * 16 + l15][kh * 32 + quad * 8]);

        // S tiles -> p -> per-wave plT[j][i]
        #pragma unroll
        for (int isub = 0; isub < 4; ++isub)
            #pragma unroll
            for (int jt = 0; jt < 2; ++jt) {
                floatx4 s = {0.f, 0.f, 0.f, 0.f};
                s = __builtin_amdgcn_mfma_f32_16x16x32_bf16(a[isub][0], g[jt][0], s, 0, 0, 0);
                s = __builtin_amdgcn_mfma_f32_16x16x32_bf16(a[isub][1], g[jt][1], s, 0, 0, 0);
                float p0 = exp2f(s[0]) * rv[isub].x;
                float p1 = exp2f(s[1]) * rv[isub].y;
                float p2 = exp2f(s[2]) * rv[isub].z;
                float p3 = exp2f(s[3]) * rv[isub].w;
                uint2 o;
                o.x = pack2bf(p0, p1);
                o.y = pack2bf(p2, p3);
                *reinterpret_cast<uint2*>(&plT[w][jt * 16 + l15][isub * 16 + quad * 4]) = o;
            }

        // PV: oacc[c,j] += h[c,i] * p[i,j]  (own wave's plT, in-wave order)
        #pragma unroll
        for (int jt = 0; jt < 2; ++jt) {
            short8 p0f = *reinterpret_cast<const short8*>(&plT[w][jt * 16 + l15][quad * 8]);
            short8 p1f = *reinterpret_cast<const short8*>(&plT[w][jt * 16 + l15][32 + quad * 8]);
            #pragma unroll
            for (int cs = 0; cs < 4; ++cs) {
                oacc[cs][jt] = __builtin_amdgcn_mfma_f32_16x16x32_bf16(hh[cs][0], p0f, oacc[cs][jt], 0, 0, 0);
                oacc[cs][jt] = __builtin_amdgcn_mfma_f32_16x16x32_bf16(hh[cs][1], p1f, oacc[cs][jt], 0, 0, 0);
            }
        }
        __syncthreads();   // protect fxs/hxs before next commit
    }

    #pragma unroll
    for (int cs = 0; cs < 4; ++cs)
        #pragma unroll
        for (int jt = 0; jt < 2; ++jt)
            #pragma unroll
            for (int r = 0; r < 4; ++r)
                atomicAdd(&opT[((size_t)b * NN + jw + jt * 16 + l15) * CP + cs * 16 + quad * 4 + r],
                          oacc[cs][jt][r]);
}

// ---------------------------------------------------------------------------
// outproj (MFMA): y^T[n][co] = scale * sum_cp opT[n][cp] Wv^T[cp][co] + x.
// ---------------------------------------------------------------------------
__global__ __launch_bounds__(256) void outproj_kernel(
    const void* __restrict__ x,
    const void* __restrict__ Wv,
    const void* __restrict__ gamma,
    const int* __restrict__ dflag,
    const float* __restrict__ sig,
    const float* __restrict__ opT,
    void* __restrict__ y)
{
    const int f32 = *dflag;
    const int n0     = blockIdx.x * 64;
    const int cobase = blockIdx.y * 128;
    const int b      = blockIdx.z;
    const int t = threadIdx.x;
    const int wv = t >> 6, l = t & 63, l15 = l & 15, quad = l >> 4;
    const float scale = ldS(gamma, 0, f32) * sig[3];

    floatx4 acc[4][2];
    #pragma unroll
    for (int ns = 0; ns < 4; ++ns)
        #pragma unroll
        for (int ct = 0; ct < 2; ++ct) acc[ns][ct] = (floatx4){0.f, 0.f, 0.f, 0.f};

    #pragma unroll
    for (int ks = 0; ks < 2; ++ks) {
        const int kb = ks * 32 + quad * 8;
        short8 a[4];
        #pragma unroll
        for (int ns = 0; ns < 4; ++ns)
            a[ns] = frag8(opT, ((long)b * NN + n0 + 16 * ns + l15) * CP + kb, 1);
        #pragma unroll
        for (int ct = 0; ct < 2; ++ct) {
            const int co = cobase + 32 * wv + 16 * ct + l15;
            short8 bfr = frag8(Wv, (long)co * CP + kb, f32);
            #pragma unroll
            for (int ns = 0; ns < 4; ++ns)
                acc[ns][ct] = __builtin_amdgcn_mfma_f32_16x16x32_bf16(a[ns], bfr, acc[ns][ct], 0, 0, 0);
        }
    }

    #pragma unroll
    for (int ns = 0; ns < 4; ++ns)
        #pragma unroll
        for (int ct = 0; ct < 2; ++ct) {
            const int co = cobase + 32 * wv + 16 * ct + l15;
            const long base = ((long)b * CC + co) * NN + n0 + 16 * ns + quad * 4;
            float4 xv = ld4(x, base, f32);
            float o0 = fmaf(scale, acc[ns][ct][0], xv.x);
            float o1 = fmaf(scale, acc[ns][ct][1], xv.y);
            float o2 = fmaf(scale, acc[ns][ct][2], xv.z);
            float o3 = fmaf(scale, acc[ns][ct][3], xv.w);
            if (f32) {
                *reinterpret_cast<float4*>((float*)y + base) = make_float4(o0, o1, o2, o3);
            } else {
                uint2 o;
                o.x = pack2bf(o0, o1);
                o.y = pack2bf(o2, o3);
                *reinterpret_cast<uint2*>((unsigned short*)y + base) = o;
            }
        }
}

// ---------------------------------------------------------------------------
extern "C" void kernel_launch(void* const* d_in, const int* in_sizes, int n_in,
                              void* d_out, int out_size, void* d_ws, size_t ws_size,
                              hipStream_t stream)
{
    const void* x  = d_in[0];
    const void* Wf = d_in[1];
    const void* Wg = d_in[2];
    const void* Wh = d_in[3];
    const void* Wv = d_in[4];
    const void* uf = d_in[5];
    const void* ug = d_in[6];
    const void* uh = d_in[7];
    const void* uv = d_in[8];
    const void* gm = d_in[9];

    // ws: dfl | sig | rl (64KB) | opT (4MB fp32) | fxT | gxT | hx (2MB bf16 each)
    char* base = (char*)d_ws;
    int*   dfl = (int*)(base);
    float* sig = (float*)(base + 512);
    float* rl  = (float*)(base + 1024);
    float* opT = (float*)(base + 1024 + 65536);
    unsigned short* fxT = (unsigned short*)(base + 1024 + 65536 + 4194304);
    unsigned short* gxT = fxT + (size_t)NB * CP * NN;
    unsigned short* hx  = gxT + (size_t)NB * CP * NN;

    hipMemsetAsync(rl, 0, 65536 + 4194304, stream);

    hipLaunchKernelGGL(detect_kernel, dim3(1), dim3(256), 0, stream,
                       (const unsigned*)x, dfl);
    hipLaunchKernelGGL(sigma_kernel, dim3(4), dim3(512), 0, stream,
                       Wf, Wg, Wh, Wv, uf, ug, uh, uv, dfl, sig);
    hipLaunchKernelGGL(proj_kernel, dim3(NN / 64, NB, 3), dim3(256), 0, stream,
                       x, Wf, Wg, Wh, dfl, sig, fxT, gxT, hx);
    hipLaunchKernelGGL(rowstats_kernel, dim3(NN / 128, JSPLIT, NB), dim3(256), 0, stream,
                       fxT, gxT, rl);
    hipLaunchKernelGGL(pv_kernel, dim3(NN / 128, ISPLIT, NB), dim3(256), 0, stream,
                       fxT, gxT, hx, rl, opT);
    hipLaunchKernelGGL(outproj_kernel, dim3(NN / 64, CC / 128, NB), dim3(256), 0, stream,
                       x, Wv, gm, dfl, sig, opT, d_out);
}

// Round 8
// 380.029 us; speedup vs baseline: 1.1358x; 1.0933x over previous
//
#include <hip/hip_runtime.h>

// SAGAN self-attention, B=4, C=512, Cp=64, N=64*64=4096. fp32 in/out
// (runtime-detected). All GEMMs on bf16 MFMA 16x16x32.
// fxT/gxT transposed [n][c] (fxT pre-scaled by log2e); hx [c][n].
// Softmax: l_i = sum_j exp2(s'), no max-subtraction (|s'| small).
// R8: pv writes per-split bf16 partials with PLAIN stores into d_out-as-
// scratch (R7 showed 165 MB HBM write traffic from device-scope atomics);
// reduce_kernel sums partials -> opTb (bf16, ws); outproj reads opTb.
// proj merged: one kernel computes f/g/h (x read once, 3x fewer HBM reads).

#define NB 4
#define CC 512
#define CP 64
#define NN 4096
#define ISPLIT 4
#define JSPLIT 8
#define LOG2E 1.4426950408889634f
#define PSTRIDE ((size_t)NB * NN * CP)   // elements per partial split

typedef __attribute__((ext_vector_type(8))) short short8;
typedef __attribute__((ext_vector_type(4))) float floatx4;

__device__ __forceinline__ float bf2f_u(unsigned short h) {
    return __uint_as_float((unsigned)h << 16);
}
__device__ __forceinline__ float bf16lo(unsigned v) { return __uint_as_float(v << 16); }
__device__ __forceinline__ float bf16hi(unsigned v) { return __uint_as_float(v & 0xffff0000u); }
__device__ __forceinline__ unsigned short f2bf(float f) {
    unsigned u = __float_as_uint(f);
    u += 0x7fffu + ((u >> 16) & 1u);   // RNE
    return (unsigned short)(u >> 16);
}
__device__ __forceinline__ unsigned pack2bf(float a, float b) {
    return (unsigned)f2bf(a) | ((unsigned)f2bf(b) << 16);
}
__device__ __forceinline__ float ldS(const void* p, long i, int f32) {
    return f32 ? ((const float*)p)[i] : bf2f_u(((const unsigned short*)p)[i]);
}
__device__ __forceinline__ float2 ld2(const void* p, long i, int f32) {
    if (f32) return *reinterpret_cast<const float2*>((const float*)p + i);
    unsigned v = *reinterpret_cast<const unsigned*>((const unsigned short*)p + i);
    return make_float2(bf16lo(v), bf16hi(v));
}
__device__ __forceinline__ float4 ld4(const void* p, long i, int f32) {
    if (f32) return *reinterpret_cast<const float4*>((const float*)p + i);
    uint2 v = *reinterpret_cast<const uint2*>((const unsigned short*)p + i);
    return make_float4(bf16lo(v.x), bf16hi(v.x), bf16lo(v.y), bf16hi(v.y));
}
__device__ __forceinline__ short8 fragbf(const unsigned short* p) {
    uint4 v = *reinterpret_cast<const uint4*>(p);
    return *reinterpret_cast<short8*>(&v);
}

// ---------------------------------------------------------------------------
// dtype detector: 1 if fp32, 0 if bf16.
// ---------------------------------------------------------------------------
__global__ __launch_bounds__(256) void detect_kernel(
    const unsigned* __restrict__ x, int* __restrict__ flag)
{
    __shared__ int red[256];
    const int t = threadIdx.x;
    int bad = 0;
    for (int i = t; i < 4096; i += 256) {
        unsigned w = x[i];
        float f0 = __uint_as_float(w << 16);
        float f1 = __uint_as_float(w & 0xffff0000u);
        float a0 = fabsf(f0), a1 = fabsf(f1);
        if (!(a0 <= 1e3f) || (f0 != 0.f && a0 < 1e-20f)) bad++;
        if (!(a1 <= 1e3f) || (f1 != 0.f && a1 < 1e-20f)) bad++;
    }
    red[t] = bad;
    __syncthreads();
    for (int s = 128; s > 0; s >>= 1) { if (t < s) red[t] += red[t + s]; __syncthreads(); }
    if (t == 0) *flag = (red[0] > 64) ? 1 : 0;
}

// ---------------------------------------------------------------------------
// sigma: v = normalize(W^T u); sigma = u^T (W v); writes 1/sigma.
// ---------------------------------------------------------------------------
__global__ __launch_bounds__(512) void sigma_kernel(
    const void* __restrict__ Wf, const void* __restrict__ Wg,
    const void* __restrict__ Wh, const void* __restrict__ Wv,
    const void* __restrict__ uf, const void* __restrict__ ug,
    const void* __restrict__ uh, const void* __restrict__ uv,
    const int* __restrict__ dflag, float* __restrict__ sig)
{
    const int f32 = *dflag;
    const int w = blockIdx.x;
    const void* W;
    const void* u;
    int R, Cc, sh;
    if (w == 0)      { W = Wf; u = uf; R = 64;  Cc = 512; sh = 9; }
    else if (w == 1) { W = Wg; u = ug; R = 64;  Cc = 512; sh = 9; }
    else if (w == 2) { W = Wh; u = uh; R = 64;  Cc = 512; sh = 9; }
    else             { W = Wv; u = uv; R = 512; Cc = 64;  sh = 6; }

    __shared__ float us[512];
    __shared__ float vs[512];
    __shared__ float red[512];
    const int t = threadIdx.x;

    if (t < R) us[t] = ldS(u, t, f32);
    __syncthreads();

    if (t < Cc) {
        float a = 0.f;
        for (int i = 0; i < R; ++i) a += ldS(W, (long)(i << sh) + t, f32) * us[i];
        vs[t] = a;
    }
    __syncthreads();

    red[t] = (t < Cc) ? vs[t] * vs[t] : 0.f;
    __syncthreads();
    for (int s = 256; s > 0; s >>= 1) { if (t < s) red[t] += red[t + s]; __syncthreads(); }
    const float inv = 1.f / (sqrtf(red[0]) + 1e-12f);
    __syncthreads();
    if (t < Cc) vs[t] *= inv;
    __syncthreads();

    float a = 0.f;
    const int total = R * Cc;
    const int mask = Cc - 1;
    for (int idx = t; idx < total; idx += 512)
        a += us[idx >> sh] * ldS(W, idx, f32) * vs[idx & mask];
    red[t] = a;
    __syncthreads();
    for (int s = 256; s > 0; s >>= 1) { if (t < s) red[t] += red[t + s]; __syncthreads(); }
    if (t == 0) sig[w] = 1.f / red[0];
}

// ---------------------------------------------------------------------------
// proj (MFMA, merged f/g/h): out^T[n][c] = sum_k x^T[n][k]*(W/sig)^T[k][c]
// for all three weights in one pass over x. grid (NN/64, NB), 256 thr.
// ---------------------------------------------------------------------------
__global__ __launch_bounds__(256) void proj_kernel(
    const void* __restrict__ x,
    const void* __restrict__ Wf,
    const void* __restrict__ Wg,
    const void* __restrict__ Wh,
    const int* __restrict__ dflag,
    const float* __restrict__ sig,
    unsigned short* __restrict__ fxT, unsigned short* __restrict__ gxT,
    unsigned short* __restrict__ hx)
{
    const int f32 = *dflag;
    const int n0 = blockIdx.x * 64;
    const int b  = blockIdx.y;
    const void* Wp[3] = {Wf, Wg, Wh};
    const float sc[3] = {sig[0] * LOG2E, sig[1], sig[2]};

    __shared__ unsigned short Wl[3][64][72];   // 27.6 KB

    const int t = threadIdx.x;
    const int wv = t >> 6, l = t & 63, l15 = l & 15, quad = l >> 4;
    const int n = n0 + 16 * wv + l15;

    floatx4 acc[3][4];
    #pragma unroll
    for (int wi = 0; wi < 3; ++wi)
        #pragma unroll
        for (int ct = 0; ct < 4; ++ct) acc[wi][ct] = (floatx4){0.f, 0.f, 0.f, 0.f};

    for (int kc = 0; kc < CC; kc += 64) {
        // stage all three W chunks (64c x 64k each), scaled -> bf16
        #pragma unroll
        for (int idx = t; idx < 6144; idx += 256) {    // wave-uniform wi per iter
            int wi  = idx >> 11;
            int rem = idx & 2047;
            int c   = rem >> 5;
            int kk  = (rem & 31) * 2;
            float2 v = ld2(Wp[wi], (long)c * CC + kc + kk, f32);
            *reinterpret_cast<unsigned*>(&Wl[wi][c][kk]) =
                pack2bf(v.x * sc[wi], v.y * sc[wi]);
        }
        __syncthreads();

        // both K-half x fragments up-front (16 loads in flight)
        short8 a[2];
        #pragma unroll
        for (int ks = 0; ks < 2; ++ks) {
            const int kbase = kc + ks * 32 + quad * 8;
            float xv[8];
            #pragma unroll
            for (int j = 0; j < 8; ++j)
                xv[j] = ldS(x, ((long)b * CC + kbase + j) * NN + n, f32);
            uint4 au;
            au.x = pack2bf(xv[0], xv[1]); au.y = pack2bf(xv[2], xv[3]);
            au.z = pack2bf(xv[4], xv[5]); au.w = pack2bf(xv[6], xv[7]);
            a[ks] = *reinterpret_cast<short8*>(&au);
        }
        #pragma unroll
        for (int ks = 0; ks < 2; ++ks)
            #pragma unroll
            for (int wi = 0; wi < 3; ++wi)
                #pragma unroll
                for (int ct = 0; ct < 4; ++ct) {
                    short8 bfr = *reinterpret_cast<const short8*>(
                        &Wl[wi][ct * 16 + l15][ks * 32 + quad * 8]);
                    acc[wi][ct] = __builtin_amdgcn_mfma_f32_16x16x32_bf16(
                        a[ks], bfr, acc[wi][ct], 0, 0, 0);
                }
        __syncthreads();
    }

    // epilogue: wi 0/1 -> transposed [n][c]; wi 2 -> hx [c][n]
    #pragma unroll
    for (int wi = 0; wi < 2; ++wi) {
        unsigned short* __restrict__ dstT = (wi == 0) ? fxT : gxT;
        #pragma unroll
        for (int ct = 0; ct < 4; ++ct)
            #pragma unroll
            for (int r = 0; r < 4; ++r)
                dstT[((size_t)b * NN + n0 + 16 * wv + quad * 4 + r) * 64 + ct * 16 + l15] =
                    f2bf(acc[wi][ct][r]);
    }
    #pragma unroll
    for (int ct = 0; ct < 4; ++ct) {
        uint2 o;
        o.x = pack2bf(acc[2][ct][0], acc[2][ct][1]);
        o.y = pack2bf(acc[2][ct][2], acc[2][ct][3]);
        *reinterpret_cast<uint2*>(
            &hx[((size_t)b * CP + ct * 16 + l15) * NN + n0 + 16 * wv + quad * 4]) = o;
    }
}

// ---------------------------------------------------------------------------
// rowstats (MFMA): rl[b,i] += sum_j exp2(s'_ij) over this block's j-range.
// Block = 128 i (wave owns 32 i, fx frags reg-resident). gx tile LDS-staged,
// reg-prefetch double-buffered. grid (NN/128, JSPLIT, NB).
// ---------------------------------------------------------------------------
__global__ __launch_bounds__(256) void rowstats_kernel(
    const unsigned short* __restrict__ fxT, const unsigned short* __restrict__ gxT,
    float* __restrict__ rl)
{
    const int iblk  = blockIdx.x * 128;
    const int jbase = blockIdx.y * (NN / JSPLIT);
    const int b     = blockIdx.z;
    const int t = threadIdx.x;
    const int w = t >> 6, l = t & 63, l15 = l & 15, quad = l >> 4;
    const int iown = iblk + w * 32;

    __shared__ __align__(16) unsigned short gxs[64][72];

    short8 a[2][2];
    #pragma unroll
    for (int isub = 0; isub < 2; ++isub)
        #pragma unroll
        for (int kh = 0; kh < 2; ++kh)
            a[isub][kh] = fragbf(fxT +
                ((size_t)b * NN + iown + isub * 16 + l15) * 64 + kh * 32 + quad * 8);

    uint4 pf[2];
    #pragma unroll
    for (int k = 0; k < 2; ++k) {
        int idx = t + k * 256;
        pf[k] = *reinterpret_cast<const uint4*>(
            gxT + ((size_t)b * NN + jbase + (idx >> 3)) * 64 + (idx & 7) * 8);
    }

    float suml[2][4];
    #pragma unroll
    for (int isub = 0; isub < 2; ++isub)
        #pragma unroll
        for (int r = 0; r < 4; ++r) suml[isub][r] = 0.f;

    const int NJ = NN / JSPLIT;
    for (int jt = 0; jt < NJ; jt += 64) {
        #pragma unroll
        for (int k = 0; k < 2; ++k) {
            int idx = t + k * 256;
            *reinterpret_cast<uint4*>(&gxs[idx >> 3][(idx & 7) * 8]) = pf[k];
        }
        __syncthreads();
        if (jt + 64 < NJ) {
            #pragma unroll
            for (int k = 0; k < 2; ++k) {
                int idx = t + k * 256;
                pf[k] = *reinterpret_cast<const uint4*>(
                    gxT + ((size_t)b * NN + jbase + jt + 64 + (idx >> 3)) * 64 + (idx & 7) * 8);
            }
        }
        #pragma unroll
        for (int jsub = 0; jsub < 4; ++jsub) {
            short8 g0 = *reinterpret_cast<const short8*>(&gxs[jsub * 16 + l15][quad * 8]);
            short8 g1 = *reinterpret_cast<const short8*>(&gxs[jsub * 16 + l15][32 + quad * 8]);
            #pragma unroll
            for (int isub = 0; isub < 2; ++isub) {
                floatx4 s = {0.f, 0.f, 0.f, 0.f};
                s = __builtin_amdgcn_mfma_f32_16x16x32_bf16(a[isub][0], g0, s, 0, 0, 0);
                s = __builtin_amdgcn_mfma_f32_16x16x32_bf16(a[isub][1], g1, s, 0, 0, 0);
                #pragma unroll
                for (int r = 0; r < 4; ++r) suml[isub][r] += exp2f(s[r]);
            }
        }
        __syncthreads();
    }

    #pragma unroll
    for (int isub = 0; isub < 2; ++isub)
        #pragma unroll
        for (int r = 0; r < 4; ++r) {
            float v = suml[isub][r];
            v += __shfl_xor(v, 1);
            v += __shfl_xor(v, 2);
            v += __shfl_xor(v, 4);
            v += __shfl_xor(v, 8);
            if (l15 == 0)
                atomicAdd(&rl[(size_t)b * NN + iown + isub * 16 + quad * 4 + r], v);
        }
}

// ---------------------------------------------------------------------------
// pv (MFMA): partial[s][b,j,c] = sum_{i in split s} hx[c,i]*exp2(s')/l_i.
// PLAIN bf16 stores (no atomics). Block = 128 j (wave owns 32 j, gx frags
// reg-resident); fx+hx tiles LDS-staged, reg-prefetch; per-wave plT.
// grid (NN/128, ISPLIT, NB).
// ---------------------------------------------------------------------------
__global__ __launch_bounds__(256) void pv_kernel(
    const unsigned short* __restrict__ fxT, const unsigned short* __restrict__ gxT,
    const unsigned short* __restrict__ hx, const float* __restrict__ rl,
    unsigned short* __restrict__ part)
{
    const int j0    = blockIdx.x * 128;
    const int split = blockIdx.y;
    const int ibase = split * (NN / ISPLIT);
    const int b     = blockIdx.z;
    const int t = threadIdx.x;
    const int w = t >> 6, l = t & 63, l15 = l & 15, quad = l >> 4;
    const int jw = j0 + w * 32;

    __shared__ __align__(16) unsigned short fxs[64][72];
    __shared__ __align__(16) unsigned short hxs[64][72];
    __shared__ __align__(16) unsigned short plT[4][32][72];
    __shared__ float rli[NN / ISPLIT];   // 4 KB

    for (int idx = t; idx < NN / ISPLIT; idx += 256)
        rli[idx] = 1.f / rl[(size_t)b * NN + ibase + idx];

    short8 g[2][2];
    #pragma unroll
    for (int jt = 0; jt < 2; ++jt)
        #pragma unroll
        for (int kh = 0; kh < 2; ++kh)
            g[jt][kh] = fragbf(gxT +
                ((size_t)b * NN + jw + jt * 16 + l15) * 64 + kh * 32 + quad * 8);

    uint4 pf_f[2], pf_h[2];
    #pragma unroll
    for (int k = 0; k < 2; ++k) {
        int idx = t + k * 256;
        pf_f[k] = *reinterpret_cast<const uint4*>(
            fxT + ((size_t)b * NN + ibase + (idx >> 3)) * 64 + (idx & 7) * 8);
        pf_h[k] = *reinterpret_cast<const uint4*>(
            hx + ((size_t)b * CP + (idx >> 3)) * NN + ibase + (idx & 7) * 8);
    }

    floatx4 oacc[4][2];
    #pragma unroll
    for (int cs = 0; cs < 4; ++cs)
        #pragma unroll
        for (int jt = 0; jt < 2; ++jt) oacc[cs][jt] = (floatx4){0.f, 0.f, 0.f, 0.f};

    const int NI = NN / ISPLIT;
    for (int it = 0; it < NI; it += 64) {
        #pragma unroll
        for (int k = 0; k < 2; ++k) {
            int idx = t + k * 256;
            *reinterpret_cast<uint4*>(&fxs[idx >> 3][(idx & 7) * 8]) = pf_f[k];
            *reinterpret_cast<uint4*>(&hxs[idx >> 3][(idx & 7) * 8]) = pf_h[k];
        }
        __syncthreads();

        if (it + 64 < NI) {
            const int i1 = ibase + it + 64;
            #pragma unroll
            for (int k = 0; k < 2; ++k) {
                int idx = t + k * 256;
                pf_f[k] = *reinterpret_cast<const uint4*>(
                    fxT + ((size_t)b * NN + i1 + (idx >> 3)) * 64 + (idx & 7) * 8);
                pf_h[k] = *reinterpret_cast<const uint4*>(
                    hx + ((size_t)b * CP + (idx >> 3)) * NN + i1 + (idx & 7) * 8);
            }
        }

        float4 rv[4];
        #pragma unroll
        for (int isub = 0; isub < 4; ++isub)
            rv[isub] = *reinterpret_cast<const float4*>(&rli[it + isub * 16 + quad * 4]);

        short8 a[4][2], hh[4][2];
        #pragma unroll
        for (int isub = 0; isub < 4; ++isub)
            #pragma unroll
            for (int kh = 0; kh < 2; ++kh)
                a[isub][kh] = *reinterpret_cast<const short8*>(
                    &fxs[isub * 16 + l15][kh * 32 + quad * 8]);
        #pragma unroll
        for (int cs = 0; cs < 4; ++cs)
            #pragma unroll
            for (int kh = 0; kh < 2; ++kh)
                hh[cs][kh] = *reinterpret_cast<const short8*>(
                    &hxs[cs * 16 + l15][kh * 32 + quad * 8]);

        #pragma unroll
        for (int isub = 0; isub < 4; ++isub)
            #pragma unroll
            for (int jt = 0; jt < 2; ++jt) {
                floatx4 s = {0.f, 0.f, 0.f, 0.f};
                s = __builtin_amdgcn_mfma_f32_16x16x32_bf16(a[isub][0], g[jt][0], s, 0, 0, 0);
                s = __builtin_amdgcn_mfma_f32_16x16x32_bf16(a[isub][1], g[jt][1], s, 0, 0, 0);
                float p0 = exp2f(s[0]) * rv[isub].x;
                float p1 = exp2f(s[1]) * rv[isub].y;
                float p2 = exp2f(s[2]) * rv[isub].z;
                float p3 = exp2f(s[3]) * rv[isub].w;
                uint2 o;
                o.x = pack2bf(p0, p1);
                o.y = pack2bf(p2, p3);
                *reinterpret_cast<uint2*>(&plT[w][jt * 16 + l15][isub * 16 + quad * 4]) = o;
            }

        #pragma unroll
        for (int jt = 0; jt < 2; ++jt) {
            short8 p0f = *reinterpret_cast<const short8*>(&plT[w][jt * 16 + l15][quad * 8]);
            short8 p1f = *reinterpret_cast<const short8*>(&plT[w][jt * 16 + l15][32 + quad * 8]);
            #pragma unroll
            for (int cs = 0; cs < 4; ++cs) {
                oacc[cs][jt] = __builtin_amdgcn_mfma_f32_16x16x32_bf16(hh[cs][0], p0f, oacc[cs][jt], 0, 0, 0);
                oacc[cs][jt] = __builtin_amdgcn_mfma_f32_16x16x32_bf16(hh[cs][1], p1f, oacc[cs][jt], 0, 0, 0);
            }
        }
        __syncthreads();
    }

    // plain bf16 partial stores (4 consecutive c per uint2)
    unsigned short* pb = part + split * PSTRIDE;
    #pragma unroll
    for (int cs = 0; cs < 4; ++cs)
        #pragma unroll
        for (int jt = 0; jt < 2; ++jt) {
            uint2 o;
            o.x = pack2bf(oacc[cs][jt][0], oacc[cs][jt][1]);
            o.y = pack2bf(oacc[cs][jt][2], oacc[cs][jt][3]);
            *reinterpret_cast<uint2*>(
                &pb[((size_t)b * NN + jw + jt * 16 + l15) * CP + cs * 16 + quad * 4]) = o;
        }
}

// ---------------------------------------------------------------------------
// reduce: opTb[e] = sum_s part[s][e]  (bf16, 8 elements/thread)
// ---------------------------------------------------------------------------
__global__ __launch_bounds__(256) void reduce_kernel(
    const unsigned short* __restrict__ part, unsigned short* __restrict__ opTb)
{
    const size_t e = ((size_t)blockIdx.x * 256 + threadIdx.x) * 8;
    float o[8] = {0.f, 0.f, 0.f, 0.f, 0.f, 0.f, 0.f, 0.f};
    #pragma unroll
    for (int s = 0; s < ISPLIT; ++s) {
        uint4 v = *reinterpret_cast<const uint4*>(part + s * PSTRIDE + e);
        o[0] += bf16lo(v.x); o[1] += bf16hi(v.x);
        o[2] += bf16lo(v.y); o[3] += bf16hi(v.y);
        o[4] += bf16lo(v.z); o[5] += bf16hi(v.z);
        o[6] += bf16lo(v.w); o[7] += bf16hi(v.w);
    }
    uint4 r;
    r.x = pack2bf(o[0], o[1]); r.y = pack2bf(o[2], o[3]);
    r.z = pack2bf(o[4], o[5]); r.w = pack2bf(o[6], o[7]);
    *reinterpret_cast<uint4*>(opTb + e) = r;
}

// ---------------------------------------------------------------------------
// outproj (MFMA): y^T[n][co] = scale * sum_cp opTb[n][cp] Wv^T[cp][co] + x.
// ---------------------------------------------------------------------------
__global__ __launch_bounds__(256) void outproj_kernel(
    const void* __restrict__ x,
    const void* __restrict__ Wv,
    const void* __restrict__ gamma,
    const int* __restrict__ dflag,
    const float* __restrict__ sig,
    const unsigned short* __restrict__ opTb,
    void* __restrict__ y)
{
    const int f32 = *dflag;
    const int n0     = blockIdx.x * 64;
    const int cobase = blockIdx.y * 128;
    const int b      = blockIdx.z;
    const int t = threadIdx.x;
    const int wv = t >> 6, l = t & 63, l15 = l & 15, quad = l >> 4;
    const float scale = ldS(gamma, 0, f32) * sig[3];

    floatx4 acc[4][2];
    #pragma unroll
    for (int ns = 0; ns < 4; ++ns)
        #pragma unroll
        for (int ct = 0; ct < 2; ++ct) acc[ns][ct] = (floatx4){0.f, 0.f, 0.f, 0.f};

    #pragma unroll
    for (int ks = 0; ks < 2; ++ks) {
        const int kb = ks * 32 + quad * 8;
        short8 a[4];
        #pragma unroll
        for (int ns = 0; ns < 4; ++ns)
            a[ns] = fragbf(opTb + ((size_t)b * NN + n0 + 16 * ns + l15) * CP + kb);
        #pragma unroll
        for (int ct = 0; ct < 2; ++ct) {
            const int co = cobase + 32 * wv + 16 * ct + l15;
            short8 bfr;
            {
                uint4 au;
                if (f32) {
                    float4 v0 = *reinterpret_cast<const float4*>((const float*)Wv + (long)co * CP + kb);
                    float4 v1 = *reinterpret_cast<const float4*>((const float*)Wv + (long)co * CP + kb + 4);
                    au.x = pack2bf(v0.x, v0.y); au.y = pack2bf(v0.z, v0.w);
                    au.z = pack2bf(v1.x, v1.y); au.w = pack2bf(v1.z, v1.w);
                } else {
                    au = *reinterpret_cast<const uint4*>((const unsigned short*)Wv + (long)co * CP + kb);
                }
                bfr = *reinterpret_cast<short8*>(&au);
            }
            #pragma unroll
            for (int ns = 0; ns < 4; ++ns)
                acc[ns][ct] = __builtin_amdgcn_mfma_f32_16x16x32_bf16(a[ns], bfr, acc[ns][ct], 0, 0, 0);
        }
    }

    #pragma unroll
    for (int ns = 0; ns < 4; ++ns)
        #pragma unroll
        for (int ct = 0; ct < 2; ++ct) {
            const int co = cobase + 32 * wv + 16 * ct + l15;
            const long base = ((long)b * CC + co) * NN + n0 + 16 * ns + quad * 4;
            float4 xv = ld4(x, base, f32);
            float o0 = fmaf(scale, acc[ns][ct][0], xv.x);
            float o1 = fmaf(scale, acc[ns][ct][1], xv.y);
            float o2 = fmaf(scale, acc[ns][ct][2], xv.z);
            float o3 = fmaf(scale, acc[ns][ct][3], xv.w);
            if (f32) {
                *reinterpret_cast<float4*>((float*)y + base) = make_float4(o0, o1, o2, o3);
            } else {
                uint2 o;
                o.x = pack2bf(o0, o1);
                o.y = pack2bf(o2, o3);
                *reinterpret_cast<uint2*>((unsigned short*)y + base) = o;
            }
        }
}

// ---------------------------------------------------------------------------
extern "C" void kernel_launch(void* const* d_in, const int* in_sizes, int n_in,
                              void* d_out, int out_size, void* d_ws, size_t ws_size,
                              hipStream_t stream)
{
    const void* x  = d_in[0];
    const void* Wf = d_in[1];
    const void* Wg = d_in[2];
    const void* Wh = d_in[3];
    const void* Wv = d_in[4];
    const void* uf = d_in[5];
    const void* ug = d_in[6];
    const void* uh = d_in[7];
    const void* uv = d_in[8];
    const void* gm = d_in[9];

    // ws: dfl | sig | rl (64KB) | opTb (2MB bf16) | fxT | gxT | hx (2MB each)
    // total ~8.4 MB. Partials (4 x 2MB bf16) live in d_out-as-scratch; d_out
    // is fully overwritten by outproj afterwards (out is 33.5 MB fp32).
    char* base = (char*)d_ws;
    int*   dfl = (int*)(base);
    float* sig = (float*)(base + 512);
    float* rl  = (float*)(base + 1024);
    unsigned short* opTb = (unsigned short*)(base + 1024 + 65536);
    unsigned short* fxT  = opTb + PSTRIDE;
    unsigned short* gxT  = fxT + PSTRIDE;
    unsigned short* hx   = gxT + PSTRIDE;
    unsigned short* part = (unsigned short*)d_out;   // 4 x 2MB partials

    hipMemsetAsync(rl, 0, 65536, stream);

    hipLaunchKernelGGL(detect_kernel, dim3(1), dim3(256), 0, stream,
                       (const unsigned*)x, dfl);
    hipLaunchKernelGGL(sigma_kernel, dim3(4), dim3(512), 0, stream,
                       Wf, Wg, Wh, Wv, uf, ug, uh, uv, dfl, sig);
    hipLaunchKernelGGL(proj_kernel, dim3(NN / 64, NB), dim3(256), 0, stream,
                       x, Wf, Wg, Wh, dfl, sig, fxT, gxT, hx);
    hipLaunchKernelGGL(rowstats_kernel, dim3(NN / 128, JSPLIT, NB), dim3(256), 0, stream,
                       fxT, gxT, rl);
    hipLaunchKernelGGL(pv_kernel, dim3(NN / 128, ISPLIT, NB), dim3(256), 0, stream,
                       fxT, gxT, hx, rl, part);
    hipLaunchKernelGGL(reduce_kernel, dim3((PSTRIDE / 8) / 256), dim3(256), 0, stream,
                       part, opTb);
    hipLaunchKernelGGL(outproj_kernel, dim3(NN / 64, CC / 128, NB), dim3(256), 0, stream,
                       x, Wv, gm, dfl, sig, opTb, d_out);
}

// Round 9
// 336.052 us; speedup vs baseline: 1.2845x; 1.1309x over previous
//
#include <hip/hip_runtime.h>

// SAGAN self-attention, B=4, C=512, Cp=64, N=64*64=4096. fp32 in/out
// (runtime-detected). All GEMMs on bf16 MFMA 16x16x32.
// fxT/gxT transposed [n][c] (fxT pre-scaled by log2e); hx [c][n].
// Softmax: l_i = sum_j exp2(s'), no max-subtraction (|s'| small).
// R9: W pre-converted once to scaled bf16 (wprep) -> proj is barrier-free
// and LDS-free (W-frags direct from global, L2-resident; x scalar loads
// software-pipelined across a fully unrolled K loop). pv writes per-split
// bf16 partials with plain stores into d_out-as-scratch; reduce sums them.

#define NB 4
#define CC 512
#define CP 64
#define NN 4096
#define ISPLIT 4
#define JSPLIT 8
#define LOG2E 1.4426950408889634f
#define PSTRIDE ((size_t)NB * NN * CP)   // elements per partial split

typedef __attribute__((ext_vector_type(8))) short short8;
typedef __attribute__((ext_vector_type(4))) float floatx4;

__device__ __forceinline__ float bf2f_u(unsigned short h) {
    return __uint_as_float((unsigned)h << 16);
}
__device__ __forceinline__ float bf16lo(unsigned v) { return __uint_as_float(v << 16); }
__device__ __forceinline__ float bf16hi(unsigned v) { return __uint_as_float(v & 0xffff0000u); }
__device__ __forceinline__ unsigned short f2bf(float f) {
    unsigned u = __float_as_uint(f);
    u += 0x7fffu + ((u >> 16) & 1u);   // RNE
    return (unsigned short)(u >> 16);
}
__device__ __forceinline__ unsigned pack2bf(float a, float b) {
    return (unsigned)f2bf(a) | ((unsigned)f2bf(b) << 16);
}
__device__ __forceinline__ float ldS(const void* p, long i, int f32) {
    return f32 ? ((const float*)p)[i] : bf2f_u(((const unsigned short*)p)[i]);
}
__device__ __forceinline__ float4 ld4(const void* p, long i, int f32) {
    if (f32) return *reinterpret_cast<const float4*>((const float*)p + i);
    uint2 v = *reinterpret_cast<const uint2*>((const unsigned short*)p + i);
    return make_float4(bf16lo(v.x), bf16hi(v.x), bf16lo(v.y), bf16hi(v.y));
}
__device__ __forceinline__ short8 fragbf(const unsigned short* p) {
    uint4 v = *reinterpret_cast<const uint4*>(p);
    return *reinterpret_cast<short8*>(&v);
}

// ---------------------------------------------------------------------------
// dtype detector: 1 if fp32, 0 if bf16.
// ---------------------------------------------------------------------------
__global__ __launch_bounds__(256) void detect_kernel(
    const unsigned* __restrict__ x, int* __restrict__ flag)
{
    __shared__ int red[256];
    const int t = threadIdx.x;
    int bad = 0;
    for (int i = t; i < 4096; i += 256) {
        unsigned w = x[i];
        float f0 = __uint_as_float(w << 16);
        float f1 = __uint_as_float(w & 0xffff0000u);
        float a0 = fabsf(f0), a1 = fabsf(f1);
        if (!(a0 <= 1e3f) || (f0 != 0.f && a0 < 1e-20f)) bad++;
        if (!(a1 <= 1e3f) || (f1 != 0.f && a1 < 1e-20f)) bad++;
    }
    red[t] = bad;
    __syncthreads();
    for (int s = 128; s > 0; s >>= 1) { if (t < s) red[t] += red[t + s]; __syncthreads(); }
    if (t == 0) *flag = (red[0] > 64) ? 1 : 0;
}

// ---------------------------------------------------------------------------
// sigma: v = normalize(W^T u); sigma = u^T (W v); writes 1/sigma.
// ---------------------------------------------------------------------------
__global__ __launch_bounds__(512) void sigma_kernel(
    const void* __restrict__ Wf, const void* __restrict__ Wg,
    const void* __restrict__ Wh, const void* __restrict__ Wv,
    const void* __restrict__ uf, const void* __restrict__ ug,
    const void* __restrict__ uh, const void* __restrict__ uv,
    const int* __restrict__ dflag, float* __restrict__ sig)
{
    const int f32 = *dflag;
    const int w = blockIdx.x;
    const void* W;
    const void* u;
    int R, Cc, sh;
    if (w == 0)      { W = Wf; u = uf; R = 64;  Cc = 512; sh = 9; }
    else if (w == 1) { W = Wg; u = ug; R = 64;  Cc = 512; sh = 9; }
    else if (w == 2) { W = Wh; u = uh; R = 64;  Cc = 512; sh = 9; }
    else             { W = Wv; u = uv; R = 512; Cc = 64;  sh = 6; }

    __shared__ float us[512];
    __shared__ float vs[512];
    __shared__ float red[512];
    const int t = threadIdx.x;

    if (t < R) us[t] = ldS(u, t, f32);
    __syncthreads();

    if (t < Cc) {
        float a = 0.f;
        for (int i = 0; i < R; ++i) a += ldS(W, (long)(i << sh) + t, f32) * us[i];
        vs[t] = a;
    }
    __syncthreads();

    red[t] = (t < Cc) ? vs[t] * vs[t] : 0.f;
    __syncthreads();
    for (int s = 256; s > 0; s >>= 1) { if (t < s) red[t] += red[t + s]; __syncthreads(); }
    const float inv = 1.f / (sqrtf(red[0]) + 1e-12f);
    __syncthreads();
    if (t < Cc) vs[t] *= inv;
    __syncthreads();

    float a = 0.f;
    const int total = R * Cc;
    const int mask = Cc - 1;
    for (int idx = t; idx < total; idx += 512)
        a += us[idx >> sh] * ldS(W, idx, f32) * vs[idx & mask];
    red[t] = a;
    __syncthreads();
    for (int s = 256; s > 0; s >>= 1) { if (t < s) red[t] += red[t + s]; __syncthreads(); }
    if (t == 0) sig[w] = 1.f / red[0];
}

// ---------------------------------------------------------------------------
// wprep: Wbf[wi][c][k] = bf16( W[wi][c][k] * scale_wi ), wi in {f,g,h}.
// 196 KB total -> L2-resident for proj. grid (64, 3), 256 thr.
// ---------------------------------------------------------------------------
__global__ __launch_bounds__(256) void wprep_kernel(
    const void* __restrict__ Wf, const void* __restrict__ Wg,
    const void* __restrict__ Wh,
    const int* __restrict__ dflag, const float* __restrict__ sig,
    unsigned short* __restrict__ Wbf)
{
    const int f32 = *dflag;
    const int row = blockIdx.x;
    const int wi  = blockIdx.y;
    const void* W = (wi == 0) ? Wf : ((wi == 1) ? Wg : Wh);
    const float scale = sig[wi] * ((wi == 0) ? LOG2E : 1.f);
    const int t = threadIdx.x;
    #pragma unroll
    for (int idx = t; idx < CC; idx += 256)
        Wbf[(((size_t)wi * 64 + row) << 9) + idx] =
            f2bf(ldS(W, (long)row * CC + idx, f32) * scale);
}

// ---------------------------------------------------------------------------
// proj (MFMA, merged f/g/h, barrier-free, LDS-free):
// out^T[n][c] = sum_k x^T[n][k] * Wbf[wi]^T[k][c].
// W-frags direct from global bf16 (L2-hot); x scalar loads pipelined across
// the fully unrolled K loop. grid (NN/64, NB), 256 thr (4 indep waves).
// ---------------------------------------------------------------------------
__global__ __launch_bounds__(256) void proj_kernel(
    const void* __restrict__ x,
    const unsigned short* __restrict__ Wbf,
    const int* __restrict__ dflag,
    unsigned short* __restrict__ fxT, unsigned short* __restrict__ gxT,
    unsigned short* __restrict__ hx)
{
    const int f32 = *dflag;
    const int n0 = blockIdx.x * 64;
    const int b  = blockIdx.y;
    const int t = threadIdx.x;
    const int wv = t >> 6, l = t & 63, l15 = l & 15, quad = l >> 4;
    const int n = n0 + 16 * wv + l15;

    floatx4 acc[3][4];
    #pragma unroll
    for (int wi = 0; wi < 3; ++wi)
        #pragma unroll
        for (int ct = 0; ct < 4; ++ct) acc[wi][ct] = (floatx4){0.f, 0.f, 0.f, 0.f};

    #pragma unroll
    for (int ks = 0; ks < 16; ++ks) {
        const int kbase = ks * 32 + quad * 8;
        // A fragment: 8 k-values of column n (scalar, stride NN)
        float xv[8];
        #pragma unroll
        for (int j = 0; j < 8; ++j)
            xv[j] = ldS(x, ((long)b * CC + kbase + j) * NN + n, f32);
        uint4 au;
        au.x = pack2bf(xv[0], xv[1]); au.y = pack2bf(xv[2], xv[3]);
        au.z = pack2bf(xv[4], xv[5]); au.w = pack2bf(xv[6], xv[7]);
        short8 a = *reinterpret_cast<short8*>(&au);
        #pragma unroll
        for (int wi = 0; wi < 3; ++wi)
            #pragma unroll
            for (int ct = 0; ct < 4; ++ct) {
                short8 bfr = fragbf(Wbf + (((size_t)wi * 64 + ct * 16 + l15) << 9) + kbase);
                acc[wi][ct] = __builtin_amdgcn_mfma_f32_16x16x32_bf16(a, bfr, acc[wi][ct], 0, 0, 0);
            }
    }

    // epilogue: wi 0/1 -> transposed [n][c]; wi 2 -> hx [c][n]
    #pragma unroll
    for (int wi = 0; wi < 2; ++wi) {
        unsigned short* __restrict__ dstT = (wi == 0) ? fxT : gxT;
        #pragma unroll
        for (int ct = 0; ct < 4; ++ct)
            #pragma unroll
            for (int r = 0; r < 4; ++r)
                dstT[((size_t)b * NN + n0 + 16 * wv + quad * 4 + r) * 64 + ct * 16 + l15] =
                    f2bf(acc[wi][ct][r]);
    }
    #pragma unroll
    for (int ct = 0; ct < 4; ++ct) {
        uint2 o;
        o.x = pack2bf(acc[2][ct][0], acc[2][ct][1]);
        o.y = pack2bf(acc[2][ct][2], acc[2][ct][3]);
        *reinterpret_cast<uint2*>(
            &hx[((size_t)b * CP + ct * 16 + l15) * NN + n0 + 16 * wv + quad * 4]) = o;
    }
}

// ---------------------------------------------------------------------------
// rowstats (MFMA): rl[b,i] += sum_j exp2(s'_ij) over this block's j-range.
// Block = 128 i (wave owns 32 i, fx frags reg-resident). gx tile LDS-staged,
// reg-prefetch double-buffered. grid (NN/128, JSPLIT, NB).
// ---------------------------------------------------------------------------
__global__ __launch_bounds__(256) void rowstats_kernel(
    const unsigned short* __restrict__ fxT, const unsigned short* __restrict__ gxT,
    float* __restrict__ rl)
{
    const int iblk  = blockIdx.x * 128;
    const int jbase = blockIdx.y * (NN / JSPLIT);
    const int b     = blockIdx.z;
    const int t = threadIdx.x;
    const int w = t >> 6, l = t & 63, l15 = l & 15, quad = l >> 4;
    const int iown = iblk + w * 32;

    __shared__ __align__(16) unsigned short gxs[64][72];

    short8 a[2][2];
    #pragma unroll
    for (int isub = 0; isub < 2; ++isub)
        #pragma unroll
        for (int kh = 0; kh < 2; ++kh)
            a[isub][kh] = fragbf(fxT +
                ((size_t)b * NN + iown + isub * 16 + l15) * 64 + kh * 32 + quad * 8);

    uint4 pf[2];
    #pragma unroll
    for (int k = 0; k < 2; ++k) {
        int idx = t + k * 256;
        pf[k] = *reinterpret_cast<const uint4*>(
            gxT + ((size_t)b * NN + jbase + (idx >> 3)) * 64 + (idx & 7) * 8);
    }

    float suml[2][4];
    #pragma unroll
    for (int isub = 0; isub < 2; ++isub)
        #pragma unroll
        for (int r = 0; r < 4; ++r) suml[isub][r] = 0.f;

    const int NJ = NN / JSPLIT;
    for (int jt = 0; jt < NJ; jt += 64) {
        #pragma unroll
        for (int k = 0; k < 2; ++k) {
            int idx = t + k * 256;
            *reinterpret_cast<uint4*>(&gxs[idx >> 3][(idx & 7) * 8]) = pf[k];
        }
        __syncthreads();
        if (jt + 64 < NJ) {
            #pragma unroll
            for (int k = 0; k < 2; ++k) {
                int idx = t + k * 256;
                pf[k] = *reinterpret_cast<const uint4*>(
                    gxT + ((size_t)b * NN + jbase + jt + 64 + (idx >> 3)) * 64 + (idx & 7) * 8);
            }
        }
        #pragma unroll
        for (int jsub = 0; jsub < 4; ++jsub) {
            short8 g0 = *reinterpret_cast<const short8*>(&gxs[jsub * 16 + l15][quad * 8]);
            short8 g1 = *reinterpret_cast<const short8*>(&gxs[jsub * 16 + l15][32 + quad * 8]);
            #pragma unroll
            for (int isub = 0; isub < 2; ++isub) {
                floatx4 s = {0.f, 0.f, 0.f, 0.f};
                s = __builtin_amdgcn_mfma_f32_16x16x32_bf16(a[isub][0], g0, s, 0, 0, 0);
                s = __builtin_amdgcn_mfma_f32_16x16x32_bf16(a[isub][1], g1, s, 0, 0, 0);
                #pragma unroll
                for (int r = 0; r < 4; ++r) suml[isub][r] += exp2f(s[r]);
            }
        }
        __syncthreads();
    }

    #pragma unroll
    for (int isub = 0; isub < 2; ++isub)
        #pragma unroll
        for (int r = 0; r < 4; ++r) {
            float v = suml[isub][r];
            v += __shfl_xor(v, 1);
            v += __shfl_xor(v, 2);
            v += __shfl_xor(v, 4);
            v += __shfl_xor(v, 8);
            if (l15 == 0)
                atomicAdd(&rl[(size_t)b * NN + iown + isub * 16 + quad * 4 + r], v);
        }
}

// ---------------------------------------------------------------------------
// pv (MFMA): partial[s][b,j,c] = sum_{i in split s} hx[c,i]*exp2(s')/l_i.
// PLAIN bf16 stores (no atomics). Block = 128 j (wave owns 32 j, gx frags
// reg-resident); fx+hx tiles LDS-staged, reg-prefetch; per-wave plT.
// grid (NN/128, ISPLIT, NB).
// ---------------------------------------------------------------------------
__global__ __launch_bounds__(256) void pv_kernel(
    const unsigned short* __restrict__ fxT, const unsigned short* __restrict__ gxT,
    const unsigned short* __restrict__ hx, const float* __restrict__ rl,
    unsigned short* __restrict__ part)
{
    const int j0    = blockIdx.x * 128;
    const int split = blockIdx.y;
    const int ibase = split * (NN / ISPLIT);
    const int b     = blockIdx.z;
    const int t = threadIdx.x;
    const int w = t >> 6, l = t & 63, l15 = l & 15, quad = l >> 4;
    const int jw = j0 + w * 32;

    __shared__ __align__(16) unsigned short fxs[64][72];
    __shared__ __align__(16) unsigned short hxs[64][72];
    __shared__ __align__(16) unsigned short plT[4][32][72];
    __shared__ float rli[NN / ISPLIT];   // 4 KB

    for (int idx = t; idx < NN / ISPLIT; idx += 256)
        rli[idx] = 1.f / rl[(size_t)b * NN + ibase + idx];

    short8 g[2][2];
    #pragma unroll
    for (int jt = 0; jt < 2; ++jt)
        #pragma unroll
        for (int kh = 0; kh < 2; ++kh)
            g[jt][kh] = fragbf(gxT +
                ((size_t)b * NN + jw + jt * 16 + l15) * 64 + kh * 32 + quad * 8);

    uint4 pf_f[2], pf_h[2];
    #pragma unroll
    for (int k = 0; k < 2; ++k) {
        int idx = t + k * 256;
        pf_f[k] = *reinterpret_cast<const uint4*>(
            fxT + ((size_t)b * NN + ibase + (idx >> 3)) * 64 + (idx & 7) * 8);
        pf_h[k] = *reinterpret_cast<const uint4*>(
            hx + ((size_t)b * CP + (idx >> 3)) * NN + ibase + (idx & 7) * 8);
    }

    floatx4 oacc[4][2];
    #pragma unroll
    for (int cs = 0; cs < 4; ++cs)
        #pragma unroll
        for (int jt = 0; jt < 2; ++jt) oacc[cs][jt] = (floatx4){0.f, 0.f, 0.f, 0.f};

    const int NI = NN / ISPLIT;
    for (int it = 0; it < NI; it += 64) {
        #pragma unroll
        for (int k = 0; k < 2; ++k) {
            int idx = t + k * 256;
            *reinterpret_cast<uint4*>(&fxs[idx >> 3][(idx & 7) * 8]) = pf_f[k];
            *reinterpret_cast<uint4*>(&hxs[idx >> 3][(idx & 7) * 8]) = pf_h[k];
        }
        __syncthreads();

        if (it + 64 < NI) {
            const int i1 = ibase + it + 64;
            #pragma unroll
            for (int k = 0; k < 2; ++k) {
                int idx = t + k * 256;
                pf_f[k] = *reinterpret_cast<const uint4*>(
                    fxT + ((size_t)b * NN + i1 + (idx >> 3)) * 64 + (idx & 7) * 8);
                pf_h[k] = *reinterpret_cast<const uint4*>(
                    hx + ((size_t)b * CP + (idx >> 3)) * NN + i1 + (idx & 7) * 8);
            }
        }

        float4 rv[4];
        #pragma unroll
        for (int isub = 0; isub < 4; ++isub)
            rv[isub] = *reinterpret_cast<const float4*>(&rli[it + isub * 16 + quad * 4]);

        short8 a[4][2], hh[4][2];
        #pragma unroll
        for (int isub = 0; isub < 4; ++isub)
            #pragma unroll
            for (int kh = 0; kh < 2; ++kh)
                a[isub][kh] = *reinterpret_cast<const short8*>(
                    &fxs[isub * 16 + l15][kh * 32 + quad * 8]);
        #pragma unroll
        for (int cs = 0; cs < 4; ++cs)
            #pragma unroll
            for (int kh = 0; kh < 2; ++kh)
                hh[cs][kh] = *reinterpret_cast<const short8*>(
                    &hxs[cs * 16 + l15][kh * 32 + quad * 8]);

        #pragma unroll
        for (int isub = 0; isub < 4; ++isub)
            #pragma unroll
            for (int jt = 0; jt < 2; ++jt) {
                floatx4 s = {0.f, 0.f, 0.f, 0.f};
                s = __builtin_amdgcn_mfma_f32_16x16x32_bf16(a[isub][0], g[jt][0], s, 0, 0, 0);
                s = __builtin_amdgcn_mfma_f32_16x16x32_bf16(a[isub][1], g[jt][1], s, 0, 0, 0);
                float p0 = exp2f(s[0]) * rv[isub].x;
                float p1 = exp2f(s[1]) * rv[isub].y;
                float p2 = exp2f(s[2]) * rv[isub].z;
                float p3 = exp2f(s[3]) * rv[isub].w;
                uint2 o;
                o.x = pack2bf(p0, p1);
                o.y = pack2bf(p2, p3);
                *reinterpret_cast<uint2*>(&plT[w][jt * 16 + l15][isub * 16 + quad * 4]) = o;
            }

        #pragma unroll
        for (int jt = 0; jt < 2; ++jt) {
            short8 p0f = *reinterpret_cast<const short8*>(&plT[w][jt * 16 + l15][quad * 8]);
            short8 p1f = *reinterpret_cast<const short8*>(&plT[w][jt * 16 + l15][32 + quad * 8]);
            #pragma unroll
            for (int cs = 0; cs < 4; ++cs) {
                oacc[cs][jt] = __builtin_amdgcn_mfma_f32_16x16x32_bf16(hh[cs][0], p0f, oacc[cs][jt], 0, 0, 0);
                oacc[cs][jt] = __builtin_amdgcn_mfma_f32_16x16x32_bf16(hh[cs][1], p1f, oacc[cs][jt], 0, 0, 0);
            }
        }
        __syncthreads();
    }

    unsigned short* pb = part + split * PSTRIDE;
    #pragma unroll
    for (int cs = 0; cs < 4; ++cs)
        #pragma unroll
        for (int jt = 0; jt < 2; ++jt) {
            uint2 o;
            o.x = pack2bf(oacc[cs][jt][0], oacc[cs][jt][1]);
            o.y = pack2bf(oacc[cs][jt][2], oacc[cs][jt][3]);
            *reinterpret_cast<uint2*>(
                &pb[((size_t)b * NN + jw + jt * 16 + l15) * CP + cs * 16 + quad * 4]) = o;
        }
}

// ---------------------------------------------------------------------------
// reduce: opTb[e] = sum_s part[s][e]  (bf16, 8 elements/thread)
// ---------------------------------------------------------------------------
__global__ __launch_bounds__(256) void reduce_kernel(
    const unsigned short* __restrict__ part, unsigned short* __restrict__ opTb)
{
    const size_t e = ((size_t)blockIdx.x * 256 + threadIdx.x) * 8;
    float o[8] = {0.f, 0.f, 0.f, 0.f, 0.f, 0.f, 0.f, 0.f};
    #pragma unroll
    for (int s = 0; s < ISPLIT; ++s) {
        uint4 v = *reinterpret_cast<const uint4*>(part + s * PSTRIDE + e);
        o[0] += bf16lo(v.x); o[1] += bf16hi(v.x);
        o[2] += bf16lo(v.y); o[3] += bf16hi(v.y);
        o[4] += bf16lo(v.z); o[5] += bf16hi(v.z);
        o[6] += bf16lo(v.w); o[7] += bf16hi(v.w);
    }
    uint4 r;
    r.x = pack2bf(o[0], o[1]); r.y = pack2bf(o[2], o[3]);
    r.z = pack2bf(o[4], o[5]); r.w = pack2bf(o[6], o[7]);
    *reinterpret_cast<uint4*>(opTb + e) = r;
}

// ---------------------------------------------------------------------------
// outproj (MFMA): y^T[n][co] = scale * sum_cp opTb[n][cp] Wv^T[cp][co] + x.
// ---------------------------------------------------------------------------
__global__ __launch_bounds__(256) void outproj_kernel(
    const void* __restrict__ x,
    const void* __restrict__ Wv,
    const void* __restrict__ gamma,
    const int* __restrict__ dflag,
    const float* __restrict__ sig,
    const unsigned short* __restrict__ opTb,
    void* __restrict__ y)
{
    const int f32 = *dflag;
    const int n0     = blockIdx.x * 64;
    const int cobase = blockIdx.y * 128;
    const int b      = blockIdx.z;
    const int t = threadIdx.x;
    const int wv = t >> 6, l = t & 63, l15 = l & 15, quad = l >> 4;
    const float scale = ldS(gamma, 0, f32) * sig[3];

    floatx4 acc[4][2];
    #pragma unroll
    for (int ns = 0; ns < 4; ++ns)
        #pragma unroll
        for (int ct = 0; ct < 2; ++ct) acc[ns][ct] = (floatx4){0.f, 0.f, 0.f, 0.f};

    #pragma unroll
    for (int ks = 0; ks < 2; ++ks) {
        const int kb = ks * 32 + quad * 8;
        short8 a[4];
        #pragma unroll
        for (int ns = 0; ns < 4; ++ns)
            a[ns] = fragbf(opTb + ((size_t)b * NN + n0 + 16 * ns + l15) * CP + kb);
        #pragma unroll
        for (int ct = 0; ct < 2; ++ct) {
            const int co = cobase + 32 * wv + 16 * ct + l15;
            short8 bfr;
            {
                uint4 au;
                if (f32) {
                    float4 v0 = *reinterpret_cast<const float4*>((const float*)Wv + (long)co * CP + kb);
                    float4 v1 = *reinterpret_cast<const float4*>((const float*)Wv + (long)co * CP + kb + 4);
                    au.x = pack2bf(v0.x, v0.y); au.y = pack2bf(v0.z, v0.w);
                    au.z = pack2bf(v1.x, v1.y); au.w = pack2bf(v1.z, v1.w);
                } else {
                    au = *reinterpret_cast<const uint4*>((const unsigned short*)Wv + (long)co * CP + kb);
                }
                bfr = *reinterpret_cast<short8*>(&au);
            }
            #pragma unroll
            for (int ns = 0; ns < 4; ++ns)
                acc[ns][ct] = __builtin_amdgcn_mfma_f32_16x16x32_bf16(a[ns], bfr, acc[ns][ct], 0, 0, 0);
        }
    }

    #pragma unroll
    for (int ns = 0; ns < 4; ++ns)
        #pragma unroll
        for (int ct = 0; ct < 2; ++ct) {
            const int co = cobase + 32 * wv + 16 * ct + l15;
            const long base = ((long)b * CC + co) * NN + n0 + 16 * ns + quad * 4;
            float4 xv = ld4(x, base, f32);
            float o0 = fmaf(scale, acc[ns][ct][0], xv.x);
            float o1 = fmaf(scale, acc[ns][ct][1], xv.y);
            float o2 = fmaf(scale, acc[ns][ct][2], xv.z);
            float o3 = fmaf(scale, acc[ns][ct][3], xv.w);
            if (f32) {
                *reinterpret_cast<float4*>((float*)y + base) = make_float4(o0, o1, o2, o3);
            } else {
                uint2 o;
                o.x = pack2bf(o0, o1);
                o.y = pack2bf(o2, o3);
                *reinterpret_cast<uint2*>((unsigned short*)y + base) = o;
            }
        }
}

// ---------------------------------------------------------------------------
extern "C" void kernel_launch(void* const* d_in, const int* in_sizes, int n_in,
                              void* d_out, int out_size, void* d_ws, size_t ws_size,
                              hipStream_t stream)
{
    const void* x  = d_in[0];
    const void* Wf = d_in[1];
    const void* Wg = d_in[2];
    const void* Wh = d_in[3];
    const void* Wv = d_in[4];
    const void* uf = d_in[5];
    const void* ug = d_in[6];
    const void* uh = d_in[7];
    const void* uv = d_in[8];
    const void* gm = d_in[9];

    // ws: dfl | sig | rl(64K) | Wbf(192K) | opTb(2M) | fxT | gxT | hx (2M each)
    // total ~8.65 MB. Partials (4 x 2MB bf16) live in d_out-as-scratch;
    // d_out fully overwritten by outproj afterwards.
    char* base = (char*)d_ws;
    int*   dfl = (int*)(base);
    float* sig = (float*)(base + 512);
    float* rl  = (float*)(base + 1024);
    unsigned short* Wbf  = (unsigned short*)(base + 1024 + 65536);
    unsigned short* opTb = Wbf + (size_t)3 * 64 * CC;
    unsigned short* fxT  = opTb + PSTRIDE;
    unsigned short* gxT  = fxT + PSTRIDE;
    unsigned short* hx   = gxT + PSTRIDE;
    unsigned short* part = (unsigned short*)d_out;   // 4 x 2MB partials

    hipMemsetAsync(rl, 0, 65536, stream);

    hipLaunchKernelGGL(detect_kernel, dim3(1), dim3(256), 0, stream,
                       (const unsigned*)x, dfl);
    hipLaunchKernelGGL(sigma_kernel, dim3(4), dim3(512), 0, stream,
                       Wf, Wg, Wh, Wv, uf, ug, uh, uv, dfl, sig);
    hipLaunchKernelGGL(wprep_kernel, dim3(64, 3), dim3(256), 0, stream,
                       Wf, Wg, Wh, dfl, sig, Wbf);
    hipLaunchKernelGGL(proj_kernel, dim3(NN / 64, NB), dim3(256), 0, stream,
                       x, Wbf, dfl, fxT, gxT, hx);
    hipLaunchKernelGGL(rowstats_kernel, dim3(NN / 128, JSPLIT, NB), dim3(256), 0, stream,
                       fxT, gxT, rl);
    hipLaunchKernelGGL(pv_kernel, dim3(NN / 128, ISPLIT, NB), dim3(256), 0, stream,
                       fxT, gxT, hx, rl, part);
    hipLaunchKernelGGL(reduce_kernel, dim3((PSTRIDE / 8) / 256), dim3(256), 0, stream,
                       part, opTb);
    hipLaunchKernelGGL(outproj_kernel, dim3(NN / 64, CC / 128, NB), dim3(256), 0, stream,
                       x, Wv, gm, dfl, sig, opTb, d_out);
}